// Round 1
// baseline (41897.446 us; speedup 1.0000x reference)
//
#include <hip/hip_runtime.h>

#define D 512
#define H 16
#define HD 32
#define LAYERS 24
#define FF 2048
#define MAX_DECODE 1500
#define TOTAL 1024
#define CACHE_ROWS (TOTAL + MAX_DECODE)   // 2524
#define VOCAB_AUD 1025

typedef unsigned short u16;
typedef __attribute__((ext_vector_type(8))) __bf16 bf16x8;
typedef __attribute__((ext_vector_type(4))) float f32x4;
typedef __attribute__((ext_vector_type(8))) u16 u16x8;
typedef __attribute__((ext_vector_type(4))) u16 u16x4;

__device__ __forceinline__ u16 f2bf(float f) {
    unsigned u = __builtin_bit_cast(unsigned, f);
    u += 0x7fff + ((u >> 16) & 1);   // RNE
    return (u16)(u >> 16);
}

// ---------------------------------------------------------------------------
// Sinusoidal PE
// ---------------------------------------------------------------------------
__device__ __forceinline__ float pe_val(int pos, int c) {
    int j = c & ~1;
    float div = __expf((float)j * -0.017988946039015984f);  // -log(10000)/512
    float ang = (float)pos * div;
    return (c & 1) ? __cosf(ang) : __sinf(ang);
}

// ---------------------------------------------------------------------------
// Transpose + fp32->bf16 convert:  W[K][N] (layer z) -> WT[N][K] bf16
// grid (N/32, K/32, L), block 256
// ---------------------------------------------------------------------------
__global__ __launch_bounds__(256) void transpose_cvt(const float* __restrict__ W,
                                                     u16* __restrict__ WT,
                                                     int K, int N) {
    const size_t lsz = (size_t)K * N;
    const float* Wl = W + blockIdx.z * lsz;
    u16* WTl = WT + blockIdx.z * lsz;
    __shared__ float T[32][33];
    const int t = threadIdx.x;
    const int k0 = blockIdx.y * 32, n0 = blockIdx.x * 32;
    {
        int r = t >> 5, c = t & 31;
#pragma unroll
        for (int i = 0; i < 4; ++i)
            T[r + 8 * i][c] = Wl[(size_t)(k0 + r + 8 * i) * N + n0 + c];
    }
    __syncthreads();
    {
        int n = t >> 3, cg = t & 7;
        u16x4 o;
#pragma unroll
        for (int j = 0; j < 4; ++j) o[j] = f2bf(T[cg * 4 + j][n]);
        *(u16x4*)&WTl[(size_t)(n0 + n) * K + k0 + cg * 4] = o;
    }
}

// ---------------------------------------------------------------------------
// bf16 MFMA GEMM: C[M,N] = A[M,K] @ BT[N,K]^T + bias.
// 128x128 tile, BK=32, 256 thr (4 waves 2x2, each 64x64 = 16 MFMA frags).
// M%128==0, N%128==0, K%32==0.
// ---------------------------------------------------------------------------
#define AP 40  // LDS pitch (u16): 80B rows, 16B-aligned, conflict-free frags

template <bool RELU, bool WF32, bool WBF16>
__global__ __launch_bounds__(256) void gemm_mfma(const u16* __restrict__ A,
                                                 const u16* __restrict__ BT,
                                                 const float* __restrict__ bias,
                                                 float* __restrict__ C,
                                                 u16* __restrict__ Cb,
                                                 int M, int K, int N) {
    __shared__ u16 As[128 * AP];
    __shared__ u16 Bs[128 * AP];
    const int tid = threadIdx.x;
    const int lane = tid & 63;
    const int wave = tid >> 6;
    const int wm = wave & 1, wn = wave >> 1;
    const int m0 = blockIdx.y * 128, n0 = blockIdx.x * 128;
    const int cr = lane & 15, qd = lane >> 4;
    f32x4 acc[4][4];
#pragma unroll
    for (int i = 0; i < 4; ++i)
#pragma unroll
        for (int j = 0; j < 4; ++j) acc[i][j] = (f32x4){0.f, 0.f, 0.f, 0.f};
    for (int k0 = 0; k0 < K; k0 += 32) {
#pragma unroll
        for (int i = 0; i < 2; ++i) {
            int slot = tid + i * 256;
            int r = slot >> 2, c = slot & 3;
            *(u16x8*)&As[r * AP + c * 8] =
                *(const u16x8*)&A[(size_t)(m0 + r) * K + k0 + c * 8];
            *(u16x8*)&Bs[r * AP + c * 8] =
                *(const u16x8*)&BT[(size_t)(n0 + r) * K + k0 + c * 8];
        }
        __syncthreads();
        bf16x8 af[4], bfr[4];
#pragma unroll
        for (int mi = 0; mi < 4; ++mi)
            af[mi] = *(const bf16x8*)&As[(wm * 64 + mi * 16 + cr) * AP + qd * 8];
#pragma unroll
        for (int ni = 0; ni < 4; ++ni)
            bfr[ni] = *(const bf16x8*)&Bs[(wn * 64 + ni * 16 + cr) * AP + qd * 8];
#pragma unroll
        for (int mi = 0; mi < 4; ++mi)
#pragma unroll
            for (int ni = 0; ni < 4; ++ni)
                acc[mi][ni] = __builtin_amdgcn_mfma_f32_16x16x32_bf16(
                    af[mi], bfr[ni], acc[mi][ni], 0, 0, 0);
        __syncthreads();
    }
#pragma unroll
    for (int mi = 0; mi < 4; ++mi)
#pragma unroll
        for (int ni = 0; ni < 4; ++ni) {
            int n = n0 + wn * 64 + ni * 16 + cr;
            float bn = bias[n];
#pragma unroll
            for (int r = 0; r < 4; ++r) {
                int mm = m0 + wm * 64 + mi * 16 + qd * 4 + r;
                float v = acc[mi][ni][r] + bn;
                if (RELU) v = fmaxf(v, 0.f);
                if (WF32) C[(size_t)mm * N + n] = v;
                if (WBF16) Cb[(size_t)mm * N + n] = f2bf(v);
            }
        }
}

// ---------------------------------------------------------------------------
// Build packed input h (fp32 + bf16)
// ---------------------------------------------------------------------------
__global__ void build_h(const int* __restrict__ prompts, const int* __restrict__ pl,
                        const int* __restrict__ ref_seq, const int* __restrict__ rl,
                        const int* __restrict__ text_seq, const int* __restrict__ tl,
                        const float* __restrict__ text_emb, const float* __restrict__ audio_emb,
                        const float* __restrict__ refproj, const float* __restrict__ textproj,
                        const float* __restrict__ alpha_text, const float* __restrict__ alpha_audio,
                        float* __restrict__ h, u16* __restrict__ hb) {
    const int t = blockIdx.x;
    const int ref_len = rl[0], text_len = tl[0], p_len = pl[0];
    const int x_len = ref_len + text_len;
    const int tot = x_len + p_len;
    const float at = alpha_text[0], aa = alpha_audio[0];
    for (int c = threadIdx.x; c < D; c += 256) {
        float val = 0.f;
        if (t < x_len) {
            float pe = at * pe_val(t, c);
            if (t < ref_len)
                val = text_emb[ref_seq[t] * D + c] + refproj[t * D + c] + pe;
            else
                val = text_emb[text_seq[t - ref_len] * D + c] + textproj[(t - ref_len) * D + c] + pe;
        } else if (t < tot) {
            int i = t - x_len;
            float pe = aa * pe_val(i, c);
            float a = (i < p_len) ? audio_emb[prompts[i] * D + c] : 0.f;
            val = a + pe;
        }
        h[t * D + c] = val;
        hb[t * D + c] = f2bf(val);
    }
}

// ---------------------------------------------------------------------------
// Copy k,v slices of qkv buffer into the layer's cache rows.
// ---------------------------------------------------------------------------
__global__ void copy_kv(const float* __restrict__ qkv, float* __restrict__ kc,
                        float* __restrict__ vc) {
    int idx = blockIdx.x * 256 + threadIdx.x;
    int row = idx >> 7, c4 = idx & 127;
    const float4* kp = (const float4*)(qkv + row * (3 * D) + D);
    const float4* vp = (const float4*)(qkv + row * (3 * D) + 2 * D);
    ((float4*)(kc + row * D))[c4] = kp[c4];
    ((float4*)(vc + row * D))[c4] = vp[c4];
}

__global__ void zero_pads(float* __restrict__ kc, float* __restrict__ vc) {
    const int per_layer = MAX_DECODE * D / 4;
    int idx = blockIdx.x * 256 + threadIdx.x;
    int l = idx / per_layer, r = idx % per_layer;
    if (l >= LAYERS) return;
    float4 z = {0.f, 0.f, 0.f, 0.f};
    float* kbase = kc + (size_t)l * CACHE_ROWS * D + (size_t)TOTAL * D;
    float* vbase = vc + (size_t)l * CACHE_ROWS * D + (size_t)TOTAL * D;
    ((float4*)kbase)[r] = z;
    ((float4*)vbase)[r] = z;
}

// ---------------------------------------------------------------------------
// Attention: block = (head, 64-q tile). K/V tiles in LDS, wave-broadcast
// reads, per-thread 16-key register score chunks (2 chunks per 32-key
// partition -> register pressure stays well under 256, no scratch spills),
// online softmax, 4-way partition combine in LDS. Output bf16.
// ---------------------------------------------------------------------------
__global__ __launch_bounds__(256) void attn2(const float* __restrict__ qkv,
                                             const int* __restrict__ rl,
                                             const int* __restrict__ tl,
                                             const int* __restrict__ pl,
                                             u16* __restrict__ outb) {
    __shared__ float smem[2 * 128 * 36];  // Ks | Vs, aliased for combine
    const int head = blockIdx.x;
    const int q0 = blockIdx.y * 64;
    const int t = threadIdx.x;
    const int qq = t & 63, p = t >> 6;
    const int qi = q0 + qq;
    const int xl = rl[0] + tl[0];
    const int tot = xl + pl[0];
    const bool vq = qi < tot;
    const float scale = 0.17677669529663687f;  // 1/sqrt(32)
    const float* qp = qkv + (size_t)qi * 1536 + head * 32;
    f32x4 qv[8];
#pragma unroll
    for (int c = 0; c < 8; ++c) qv[c] = *(const f32x4*)(qp + c * 4);
    f32x4 o[8];
#pragma unroll
    for (int c = 0; c < 8; ++c) o[c] = (f32x4){0.f, 0.f, 0.f, 0.f};
    float m = -3.0e38f, l = 0.f;
    for (int kt = 0; kt < 8; ++kt) {
        {
            int row = t >> 1, half = t & 1;
            const float* kp = qkv + (size_t)(kt * 128 + row) * 1536 + 512 + head * 32 + half * 16;
            const float* vp = kp + 512;
#pragma unroll
            for (int i = 0; i < 4; ++i) {
                *(f32x4*)&smem[row * 36 + half * 16 + i * 4] = *(const f32x4*)(kp + i * 4);
                *(f32x4*)&smem[128 * 36 + row * 36 + half * 16 + i * 4] = *(const f32x4*)(vp + i * 4);
            }
        }
        __syncthreads();
#pragma unroll
        for (int hlf = 0; hlf < 2; ++hlf) {
            const int kbase = p * 32 + hlf * 16;
            float sc[16];
            float tmax = -3.0e38f;
#pragma unroll
            for (int kk = 0; kk < 16; ++kk) {
                const float* kr = &smem[(kbase + kk) * 36];  // wave-uniform -> LDS broadcast
                f32x4 a = (f32x4){0.f, 0.f, 0.f, 0.f};
#pragma unroll
                for (int c = 0; c < 8; ++c) a += qv[c] * *(const f32x4*)(kr + c * 4);
                float s = (a.x + a.y + a.z + a.w) * scale;
                int kg = kt * 128 + kbase + kk;
                bool vk = kg < tot;
                bool inv = (!vq) || (!vk) ||
                           ((qi < xl) ? (kg >= xl) : ((kg >= xl) && (kg > qi)));
                s = inv ? -1.0e9f : s;
                sc[kk] = s;
                tmax = fmaxf(tmax, s);
            }
            // fence: keep the scheduler from pipelining PV loads into the
            // QK live range (that pipelining is what spilled the old version)
            __builtin_amdgcn_sched_barrier(0);
            float mn = fmaxf(m, tmax);
            float f = __expf(m - mn);
            l *= f;
#pragma unroll
            for (int c = 0; c < 8; ++c) o[c] *= f;
#pragma unroll
            for (int kk = 0; kk < 16; ++kk) {
                float pw = __expf(sc[kk] - mn);
                l += pw;
                const float* vr = &smem[128 * 36 + (kbase + kk) * 36];  // wave-uniform
#pragma unroll
                for (int c = 0; c < 8; ++c) o[c] += pw * *(const f32x4*)(vr + c * 4);
            }
            m = mn;
            __builtin_amdgcn_sched_barrier(0);
        }
        __syncthreads();
    }
    {   // write partials: layout per (p,q): [m, l, _, _, o0..o31], stride 36
        int base = (p * 64 + qq) * 36;
        smem[base] = m;
        smem[base + 1] = l;
#pragma unroll
        for (int c = 0; c < 8; ++c) *(f32x4*)&smem[base + 4 + c * 4] = o[c];
    }
    __syncthreads();
    {
        int dc = t >> 6;
        float mp[4], lp[4];
        float M2 = -3.0e38f;
#pragma unroll
        for (int pp = 0; pp < 4; ++pp) {
            mp[pp] = smem[(pp * 64 + qq) * 36];
            lp[pp] = smem[(pp * 64 + qq) * 36 + 1];
            M2 = fmaxf(M2, mp[pp]);
        }
        float L = 0.f, w[4];
#pragma unroll
        for (int pp = 0; pp < 4; ++pp) {
            w[pp] = __expf(mp[pp] - M2);
            L += lp[pp] * w[pp];
        }
        float invL = 1.f / L;
#pragma unroll
        for (int j = 0; j < 8; ++j) {
            int d = dc * 8 + j;
            float val = 0.f;
#pragma unroll
            for (int pp = 0; pp < 4; ++pp)
                val += smem[(pp * 64 + qq) * 36 + 4 + d] * w[pp];
            outb[(size_t)qi * D + head * HD + d] = f2bf(val * invL);
        }
    }
}

// ---------------------------------------------------------------------------
// h = LayerNorm(res + proj) * w + b  -> fp32 h AND bf16 hb
// ---------------------------------------------------------------------------
__global__ __launch_bounds__(256) void add_ln(const float* __restrict__ res,
                                              const float* __restrict__ proj,
                                              const float* __restrict__ lw,
                                              const float* __restrict__ lb,
                                              float* __restrict__ hout,
                                              u16* __restrict__ hbout) {
    const int row = blockIdx.x, tid = threadIdx.x;
    __shared__ float red[8];
    const float x0 = res[row * D + tid] + proj[row * D + tid];
    const float x1 = res[row * D + tid + 256] + proj[row * D + tid + 256];
    float s = x0 + x1, s2 = x0 * x0 + x1 * x1;
    for (int o = 32; o > 0; o >>= 1) {
        s += __shfl_down(s, o);
        s2 += __shfl_down(s2, o);
    }
    if ((tid & 63) == 0) {
        red[tid >> 6] = s;
        red[4 + (tid >> 6)] = s2;
    }
    __syncthreads();
    const float mean = (red[0] + red[1] + red[2] + red[3]) * (1.f / 512.f);
    const float var = (red[4] + red[5] + red[6] + red[7]) * (1.f / 512.f) - mean * mean;
    const float r = rsqrtf(var + 1e-5f);
    float y0 = (x0 - mean) * r * lw[tid] + lb[tid];
    float y1 = (x1 - mean) * r * lw[tid + 256] + lb[tid + 256];
    hout[row * D + tid] = y0;
    hout[row * D + tid + 256] = y1;
    hbout[row * D + tid] = f2bf(y0);
    hbout[row * D + tid + 256] = f2bf(y1);
}

// ---------------------------------------------------------------------------
__global__ void logits_kernel(const float* __restrict__ h, const float* __restrict__ pw,
                              const float* __restrict__ pb, const int* __restrict__ rl,
                              const int* __restrict__ tl, const int* __restrict__ pl,
                              float* __restrict__ out) {
    const int n = blockIdx.x * 256 + threadIdx.x;
    if (n >= VOCAB_AUD) return;
    int tot = rl[0] + tl[0] + pl[0];
    int last = tot - 1;
    if (last < 0) last = 0;
    const float* hr = h + last * D;
    float acc = 0.f;
    for (int d = 0; d < D; ++d) acc += hr[d] * pw[d * VOCAB_AUD + n];
    out[n] = acc + pb[n];
}

__global__ void finalize_kernel(const float* __restrict__ logits, const int* __restrict__ rl,
                                const int* __restrict__ tl, const int* __restrict__ pl,
                                float* __restrict__ out) {
    __shared__ float vals[1024];
    __shared__ int idxs[1024];
    const int tid = threadIdx.x;
    float v = logits[tid];
    int bi = tid;
    if (tid == 0 && logits[1024] > v) { v = logits[1024]; bi = 1024; }
    vals[tid] = v;
    idxs[tid] = bi;
    __syncthreads();
    for (int s2 = 512; s2 > 0; s2 >>= 1) {
        if (tid < s2) {
            float ov = vals[tid + s2];
            int oi = idxs[tid + s2];
            if (ov > vals[tid] || (ov == vals[tid] && oi < idxs[tid])) {
                vals[tid] = ov;
                idxs[tid] = oi;
            }
        }
        __syncthreads();
    }
    if (tid == 0) {
        out[1025] = (float)idxs[0];
        out[1026] = (idxs[0] == 1024) ? 1.f : 0.f;
        out[1027] = (float)(rl[0] + tl[0] + pl[0]);
        out[1028] = (float)pl[0];
    }
}

// ---------------------------------------------------------------------------
extern "C" void kernel_launch(void* const* d_in, const int* in_sizes, int n_in,
                              void* d_out, int out_size, void* d_ws, size_t ws_size,
                              hipStream_t stream) {
    const int* prompts = (const int*)d_in[0];
    const int* p_len = (const int*)d_in[1];
    const int* ref_seq = (const int*)d_in[2];
    const int* r_len = (const int*)d_in[3];
    const int* text_seq = (const int*)d_in[4];
    const int* t_len = (const int*)d_in[5];
    const float* ref_bert = (const float*)d_in[6];
    const float* text_bert = (const float*)d_in[7];
    const float* text_emb = (const float*)d_in[8];
    const float* audio_emb = (const float*)d_in[9];
    const float* bert_w = (const float*)d_in[10];
    const float* bert_b = (const float*)d_in[11];
    const float* alpha_text = (const float*)d_in[12];
    const float* alpha_audio = (const float*)d_in[13];
    const float* qkv_w = (const float*)d_in[14];
    const float* qkv_b = (const float*)d_in[15];
    const float* out_w = (const float*)d_in[16];
    const float* out_b = (const float*)d_in[17];
    const float* ln1_w = (const float*)d_in[18];
    const float* ln1_b = (const float*)d_in[19];
    const float* ff1_w = (const float*)d_in[20];
    const float* ff1_b = (const float*)d_in[21];
    const float* ff2_w = (const float*)d_in[22];
    const float* ff2_b = (const float*)d_in[23];
    const float* ln2_w = (const float*)d_in[24];
    const float* ln2_b = (const float*)d_in[25];
    const float* pred_w = (const float*)d_in[26];
    const float* pred_b = (const float*)d_in[27];

    // ---- workspace carve-up ----
    float* ws = (float*)d_ws;
    float* h = ws;                       // 524288 f
    float* proj = h + 524288;            // 524288 f
    float* qkvb = proj + 524288;         // 1572864 f
    float* refp = qkvb + 1572864;        // 131072 f
    float* textp = refp + 131072;        // 131072 f
    u16* hb = (u16*)(textp + 131072);    // 524288 u
    u16* attn_ob = hb + 524288;          // 524288 u
    u16* ffb = attn_ob + 524288;         // 2097152 u
    u16* refT = ffb + 2097152;           // 262144 u
    u16* textT = refT + 262144;          // 262144 u
    u16* bertwT = textT + 262144;        // 524288 u
    u16* wbase = bertwT + 524288;

    const size_t W_QKV = (size_t)D * 3 * D;      // 786432
    const size_t W_OUT = (size_t)D * D;          // 262144
    const size_t W_FF1 = (size_t)D * FF;         // 1048576
    const size_t W_FF2 = (size_t)FF * D;         // 1048576
    const size_t W_ALL = W_QKV + W_OUT + W_FF1 + W_FF2;  // 3145728 per layer

    const size_t need_full = ((char*)(wbase + LAYERS * W_ALL) - (char*)ws);
    const bool full = ws_size >= need_full;

    u16* qkvT = wbase;
    u16* outT = qkvT + (full ? LAYERS * W_QKV : 0);
    u16* ff1T = outT + (full ? LAYERS * W_OUT : 0);
    u16* ff2T = ff1T + (full ? LAYERS * W_FF1 : 0);
    if (!full) {  // per-layer scratch slots
        qkvT = wbase;
        outT = qkvT + W_QKV;
        ff1T = outT + W_OUT;
        ff2T = ff1T + W_FF1;
    }

    float* out = (float*)d_out;
    float* kc = out + 1029;
    float* vc = out + 1029 + (size_t)LAYERS * CACHE_ROWS * D;

    // zero decode-pad rows of caches
    {
        int total4 = LAYERS * (MAX_DECODE * D / 4);
        zero_pads<<<(total4 + 255) / 256, 256, 0, stream>>>(kc, vc);
    }

    // transpose+convert: bert inputs and bert weight
    transpose_cvt<<<dim3(256 / 32, 1024 / 32, 1), 256, 0, stream>>>(ref_bert, refT, 1024, 256);
    transpose_cvt<<<dim3(256 / 32, 1024 / 32, 1), 256, 0, stream>>>(text_bert, textT, 1024, 256);
    transpose_cvt<<<dim3(D / 32, 1024 / 32, 1), 256, 0, stream>>>(bert_w, bertwT, 1024, D);
    if (full) {
        transpose_cvt<<<dim3(3 * D / 32, D / 32, LAYERS), 256, 0, stream>>>(qkv_w, qkvT, D, 3 * D);
        transpose_cvt<<<dim3(D / 32, D / 32, LAYERS), 256, 0, stream>>>(out_w, outT, D, D);
        transpose_cvt<<<dim3(FF / 32, D / 32, LAYERS), 256, 0, stream>>>(ff1_w, ff1T, D, FF);
        transpose_cvt<<<dim3(D / 32, FF / 32, LAYERS), 256, 0, stream>>>(ff2_w, ff2T, FF, D);
    }

    // bert projections (MFMA): refp = refT(256x1024) @ bertwT^T + bert_b
    gemm_mfma<false, true, false><<<dim3(D / 128, 256 / 128), 256, 0, stream>>>(
        refT, bertwT, bert_b, refp, nullptr, 256, 1024, D);
    gemm_mfma<false, true, false><<<dim3(D / 128, 256 / 128), 256, 0, stream>>>(
        textT, bertwT, bert_b, textp, nullptr, 256, 1024, D);

    build_h<<<TOTAL, 256, 0, stream>>>(prompts, p_len, ref_seq, r_len, text_seq, t_len,
                                       text_emb, audio_emb, refp, textp,
                                       alpha_text, alpha_audio, h, hb);

    for (int l = 0; l < LAYERS; ++l) {
        u16 *wQ, *wO, *wF1, *wF2;
        if (full) {
            wQ = qkvT + l * W_QKV;
            wO = outT + l * W_OUT;
            wF1 = ff1T + l * W_FF1;
            wF2 = ff2T + l * W_FF2;
        } else {
            transpose_cvt<<<dim3(3 * D / 32, D / 32, 1), 256, 0, stream>>>(
                qkv_w + l * W_QKV, qkvT, D, 3 * D);
            transpose_cvt<<<dim3(D / 32, D / 32, 1), 256, 0, stream>>>(
                out_w + l * W_OUT, outT, D, D);
            transpose_cvt<<<dim3(FF / 32, D / 32, 1), 256, 0, stream>>>(
                ff1_w + l * W_FF1, ff1T, D, FF);
            transpose_cvt<<<dim3(D / 32, FF / 32, 1), 256, 0, stream>>>(
                ff2_w + l * W_FF2, ff2T, FF, D);
            wQ = qkvT; wO = outT; wF1 = ff1T; wF2 = ff2T;
        }
        // qkv = hb @ wQ^T + b
        gemm_mfma<false, true, false><<<dim3(3 * D / 128, TOTAL / 128), 256, 0, stream>>>(
            hb, wQ, qkv_b + (size_t)l * 3 * D, qkvb, nullptr, TOTAL, D, 3 * D);
        copy_kv<<<TOTAL * (D / 4) / 256, 256, 0, stream>>>(
            qkvb, kc + (size_t)l * CACHE_ROWS * D, vc + (size_t)l * CACHE_ROWS * D);
        attn2<<<dim3(H, TOTAL / 64), 256, 0, stream>>>(qkvb, r_len, t_len, p_len, attn_ob);
        gemm_mfma<false, true, false><<<dim3(D / 128, TOTAL / 128), 256, 0, stream>>>(
            attn_ob, wO, out_b + (size_t)l * D, proj, nullptr, TOTAL, D, D);
        add_ln<<<TOTAL, 256, 0, stream>>>(h, proj, ln1_w + l * D, ln1_b + l * D, h, hb);
        gemm_mfma<true, false, true><<<dim3(FF / 128, TOTAL / 128), 256, 0, stream>>>(
            hb, wF1, ff1_b + (size_t)l * FF, nullptr, ffb, TOTAL, D, FF);
        gemm_mfma<false, true, false><<<dim3(D / 128, TOTAL / 128), 256, 0, stream>>>(
            ffb, wF2, ff2_b + (size_t)l * D, proj, nullptr, TOTAL, FF, D);
        add_ln<<<TOTAL, 256, 0, stream>>>(h, proj, ln2_w + l * D, ln2_b + l * D, h, hb);
    }

    logits_kernel<<<(VOCAB_AUD + 255) / 256, 256, 0, stream>>>(
        h, pred_w, pred_b, r_len, t_len, p_len, out);
    finalize_kernel<<<1, 1024, 0, stream>>>(out, r_len, t_len, p_len, out);
}

// Round 3
// 3735.212 us; speedup vs baseline: 11.2169x; 11.2169x over previous
//
#include <hip/hip_runtime.h>

#define D 512
#define H 16
#define HD 32
#define LAYERS 24
#define FF 2048
#define MAX_DECODE 1500
#define TOTAL 1024
#define CACHE_ROWS (TOTAL + MAX_DECODE)   // 2524
#define VOCAB_AUD 1025

typedef unsigned short u16;
typedef __attribute__((ext_vector_type(8))) __bf16 bf16x8;
typedef __attribute__((ext_vector_type(4))) float f32x4;
typedef __attribute__((ext_vector_type(8))) u16 u16x8;
typedef __attribute__((ext_vector_type(4))) u16 u16x4;
typedef __attribute__((ext_vector_type(8))) _Float16 f16x8;
typedef __attribute__((ext_vector_type(4))) _Float16 f16x4;

__device__ __forceinline__ u16 f2bf(float f) {
    unsigned u = __builtin_bit_cast(unsigned, f);
    u += 0x7fff + ((u >> 16) & 1);   // RNE
    return (u16)(u >> 16);
}

__device__ __forceinline__ u16 f2h(float f) {
    _Float16 h = (_Float16)f;
    return __builtin_bit_cast(u16, h);
}

// ---------------------------------------------------------------------------
// Sinusoidal PE
// ---------------------------------------------------------------------------
__device__ __forceinline__ float pe_val(int pos, int c) {
    int j = c & ~1;
    float div = __expf((float)j * -0.017988946039015984f);  // -log(10000)/512
    float ang = (float)pos * div;
    return (c & 1) ? __cosf(ang) : __sinf(ang);
}

// ---------------------------------------------------------------------------
// Transpose + fp32->f16/bf16 convert:  W[K][N] (layer z) -> WT[N][K]
// grid (N/32, K/32, L), block 256
// ---------------------------------------------------------------------------
template <bool F16>
__global__ __launch_bounds__(256) void transpose_cvt(const float* __restrict__ W,
                                                     u16* __restrict__ WT,
                                                     int K, int N) {
    const size_t lsz = (size_t)K * N;
    const float* Wl = W + blockIdx.z * lsz;
    u16* WTl = WT + blockIdx.z * lsz;
    __shared__ float T[32][33];
    const int t = threadIdx.x;
    const int k0 = blockIdx.y * 32, n0 = blockIdx.x * 32;
    {
        int r = t >> 5, c = t & 31;
#pragma unroll
        for (int i = 0; i < 4; ++i)
            T[r + 8 * i][c] = Wl[(size_t)(k0 + r + 8 * i) * N + n0 + c];
    }
    __syncthreads();
    {
        int n = t >> 3, cg = t & 7;
        u16x4 o;
#pragma unroll
        for (int j = 0; j < 4; ++j) o[j] = F16 ? f2h(T[cg * 4 + j][n]) : f2bf(T[cg * 4 + j][n]);
        *(u16x4*)&WTl[(size_t)(n0 + n) * K + k0 + cg * 4] = o;
    }
}

// ---------------------------------------------------------------------------
// bf16 MFMA GEMM: C[M,N] = A[M,K] @ BT[N,K]^T + bias.
// 128x128 tile, BK=32, 256 thr (4 waves 2x2, each 64x64 = 16 MFMA frags).
// M%128==0, N%128==0, K%32==0.  Optional second output Cb (bf16 or f16 bits).
// ---------------------------------------------------------------------------
#define AP 40  // LDS pitch (u16): 80B rows, 16B-aligned, conflict-free frags

template <bool RELU, bool WF32, bool WBF16, bool CF16>
__global__ __launch_bounds__(256) void gemm_mfma(const u16* __restrict__ A,
                                                 const u16* __restrict__ BT,
                                                 const float* __restrict__ bias,
                                                 float* __restrict__ C,
                                                 u16* __restrict__ Cb,
                                                 int M, int K, int N) {
    __shared__ u16 As[128 * AP];
    __shared__ u16 Bs[128 * AP];
    const int tid = threadIdx.x;
    const int lane = tid & 63;
    const int wave = tid >> 6;
    const int wm = wave & 1, wn = wave >> 1;
    const int m0 = blockIdx.y * 128, n0 = blockIdx.x * 128;
    const int cr = lane & 15, qd = lane >> 4;
    f32x4 acc[4][4];
#pragma unroll
    for (int i = 0; i < 4; ++i)
#pragma unroll
        for (int j = 0; j < 4; ++j) acc[i][j] = (f32x4){0.f, 0.f, 0.f, 0.f};
    for (int k0 = 0; k0 < K; k0 += 32) {
#pragma unroll
        for (int i = 0; i < 2; ++i) {
            int slot = tid + i * 256;
            int r = slot >> 2, c = slot & 3;
            *(u16x8*)&As[r * AP + c * 8] =
                *(const u16x8*)&A[(size_t)(m0 + r) * K + k0 + c * 8];
            *(u16x8*)&Bs[r * AP + c * 8] =
                *(const u16x8*)&BT[(size_t)(n0 + r) * K + k0 + c * 8];
        }
        __syncthreads();
        bf16x8 af[4], bfr[4];
#pragma unroll
        for (int mi = 0; mi < 4; ++mi)
            af[mi] = *(const bf16x8*)&As[(wm * 64 + mi * 16 + cr) * AP + qd * 8];
#pragma unroll
        for (int ni = 0; ni < 4; ++ni)
            bfr[ni] = *(const bf16x8*)&Bs[(wn * 64 + ni * 16 + cr) * AP + qd * 8];
#pragma unroll
        for (int mi = 0; mi < 4; ++mi)
#pragma unroll
            for (int ni = 0; ni < 4; ++ni)
                acc[mi][ni] = __builtin_amdgcn_mfma_f32_16x16x32_bf16(
                    af[mi], bfr[ni], acc[mi][ni], 0, 0, 0);
        __syncthreads();
    }
#pragma unroll
    for (int mi = 0; mi < 4; ++mi)
#pragma unroll
        for (int ni = 0; ni < 4; ++ni) {
            int n = n0 + wn * 64 + ni * 16 + cr;
            float bn = bias[n];
#pragma unroll
            for (int r = 0; r < 4; ++r) {
                int mm = m0 + wm * 64 + mi * 16 + qd * 4 + r;
                float v = acc[mi][ni][r] + bn;
                if (RELU) v = fmaxf(v, 0.f);
                if (WF32) C[(size_t)mm * N + n] = v;
                if (WBF16) Cb[(size_t)mm * N + n] = CF16 ? f2h(v) : f2bf(v);
            }
        }
}

// ---------------------------------------------------------------------------
// Build packed input h (fp32 + bf16)
// ---------------------------------------------------------------------------
__global__ void build_h(const int* __restrict__ prompts, const int* __restrict__ pl,
                        const int* __restrict__ ref_seq, const int* __restrict__ rl,
                        const int* __restrict__ text_seq, const int* __restrict__ tl,
                        const float* __restrict__ text_emb, const float* __restrict__ audio_emb,
                        const float* __restrict__ refproj, const float* __restrict__ textproj,
                        const float* __restrict__ alpha_text, const float* __restrict__ alpha_audio,
                        float* __restrict__ h, u16* __restrict__ hb) {
    const int t = blockIdx.x;
    const int ref_len = rl[0], text_len = tl[0], p_len = pl[0];
    const int x_len = ref_len + text_len;
    const int tot = x_len + p_len;
    const float at = alpha_text[0], aa = alpha_audio[0];
    for (int c = threadIdx.x; c < D; c += 256) {
        float val = 0.f;
        if (t < x_len) {
            float pe = at * pe_val(t, c);
            if (t < ref_len)
                val = text_emb[ref_seq[t] * D + c] + refproj[t * D + c] + pe;
            else
                val = text_emb[text_seq[t - ref_len] * D + c] + textproj[(t - ref_len) * D + c] + pe;
        } else if (t < tot) {
            int i = t - x_len;
            float pe = aa * pe_val(i, c);
            float a = (i < p_len) ? audio_emb[prompts[i] * D + c] : 0.f;
            val = a + pe;
        }
        h[t * D + c] = val;
        hb[t * D + c] = f2bf(val);
    }
}

// ---------------------------------------------------------------------------
// Copy k,v slices of qkv buffer into the layer's cache rows.
// ---------------------------------------------------------------------------
__global__ void copy_kv(const float* __restrict__ qkv, float* __restrict__ kc,
                        float* __restrict__ vc) {
    int idx = blockIdx.x * 256 + threadIdx.x;
    int row = idx >> 7, c4 = idx & 127;
    const float4* kp = (const float4*)(qkv + row * (3 * D) + D);
    const float4* vp = (const float4*)(qkv + row * (3 * D) + 2 * D);
    ((float4*)(kc + row * D))[c4] = kp[c4];
    ((float4*)(vc + row * D))[c4] = vp[c4];
}

__global__ void zero_pads(float* __restrict__ kc, float* __restrict__ vc) {
    const int per_layer = MAX_DECODE * D / 4;
    int idx = blockIdx.x * 256 + threadIdx.x;
    int l = idx / per_layer, r = idx % per_layer;
    if (l >= LAYERS) return;
    float4 z = {0.f, 0.f, 0.f, 0.f};
    float* kbase = kc + (size_t)l * CACHE_ROWS * D + (size_t)TOTAL * D;
    float* vbase = vc + (size_t)l * CACHE_ROWS * D + (size_t)TOTAL * D;
    ((float4*)kbase)[r] = z;
    ((float4*)vbase)[r] = z;
}

// ---------------------------------------------------------------------------
// MFMA flash attention.  Block = (head, 64 q rows), 256 thr = 4 waves,
// each wave owns 16 q rows.  Key loop: 8 tiles of 128 keys.
//  - S^T = mfma(K_frag, Q_frag): q = lane&15, key = (lane>>4)*4+reg
//    -> softmax over keys is in-lane + shfl_xor(16/32).
//  - P (f16) goes through a PER-WAVE LDS buffer (no barrier needed).
//  - PV: A = P rows from LDS, B = V^T rows (pre-transposed f16 in global).
// All operands f16, accumulation f32 (inside MFMA).
// ---------------------------------------------------------------------------
#define KP 40    // K tile pitch (u16)
#define VP 136   // Vt / P pitch (u16)

__global__ __launch_bounds__(256) void attn_mfma(const u16* __restrict__ qkvh,
                                                 const u16* __restrict__ vth,
                                                 const int* __restrict__ rl,
                                                 const int* __restrict__ tl,
                                                 const int* __restrict__ pl,
                                                 u16* __restrict__ outb) {
    __shared__ u16 lds[128 * KP + 32 * VP + 4 * 16 * VP];
    u16* Kl = lds;                         // [128][KP]
    u16* Vl = lds + 128 * KP;              // [32][VP]
    u16* Pl = lds + 128 * KP + 32 * VP;    // [4 waves][16 q][VP]
    const int h = blockIdx.x;
    const int q0 = blockIdx.y * 64;
    const int t = threadIdx.x;
    const int lane = t & 63, w = t >> 6;
    const int c = lane & 15, g = lane >> 4;
    const int xl = rl[0] + tl[0];
    const int tot = xl + pl[0];
    const float scale = 0.17677669529663687f;  // 1/sqrt(32)
    const int qi = q0 + w * 16 + c;            // this lane's q (stats/P space)
    // valid keys for qi are exactly kg < Lq
    const int Lq = (qi < tot) ? ((qi < xl) ? xl : qi + 1) : 0;
    // Q fragment (B operand): row = qi, d-octet g
    f16x8 qf = *(const f16x8*)&qkvh[(size_t)qi * 1536 + h * 32 + g * 8];
    f32x4 o[2];
    o[0] = (f32x4){0.f, 0.f, 0.f, 0.f};
    o[1] = (f32x4){0.f, 0.f, 0.f, 0.f};
    float m = -3.0e38f, l = 0.f;
    u16* Pw = Pl + w * 16 * VP;
    const f32x4 zero = (f32x4){0.f, 0.f, 0.f, 0.f};
    for (int kt = 0; kt < 8; ++kt) {
        {   // stage K tile [128 keys][32 d]
            int row = t >> 1, half = t & 1;
            const u16* src = qkvh + (size_t)(kt * 128 + row) * 1536 + 512 + h * 32 + half * 16;
            *(u16x8*)&Kl[row * KP + half * 16] = *(const u16x8*)(src);
            *(u16x8*)&Kl[row * KP + half * 16 + 8] = *(const u16x8*)(src + 8);
        }
        {   // stage V^T tile [32 d][128 keys] (16 u16 per thread = full 4096)
            int d = t >> 3, seg = t & 7;
            const u16* src = &vth[(size_t)(h * 32 + d) * 1024 + kt * 128 + seg * 16];
            *(u16x8*)&Vl[d * VP + seg * 16] = *(const u16x8*)(src);
            *(u16x8*)&Vl[d * VP + seg * 16 + 8] = *(const u16x8*)(src + 8);
        }
        __syncthreads();
        // S^T: 8 fragments of 16 keys each
        f32x4 s[8];
#pragma unroll
        for (int f = 0; f < 8; ++f) {
            f16x8 kf = *(const f16x8*)&Kl[(f * 16 + c) * KP + g * 8];
            s[f] = __builtin_amdgcn_mfma_f32_16x16x32_f16(kf, qf, zero, 0, 0, 0);
        }
        // scale + mask + tile max
        float tmax = -3.0e38f;
#pragma unroll
        for (int f = 0; f < 8; ++f)
#pragma unroll
            for (int r = 0; r < 4; ++r) {
                int kg = kt * 128 + f * 16 + g * 4 + r;
                float v = (kg < Lq) ? s[f][r] * scale : -1.0e9f;
                s[f][r] = v;
                tmax = fmaxf(tmax, v);
            }
        tmax = fmaxf(tmax, __shfl_xor(tmax, 16));
        tmax = fmaxf(tmax, __shfl_xor(tmax, 32));
        const float mn = fmaxf(m, tmax);
        const float fsc = __expf(m - mn);
        m = mn;
        // exp, pack to f16, stash P in per-wave LDS
        float lsum = 0.f;
#pragma unroll
        for (int f = 0; f < 8; ++f) {
            float p0 = __expf(s[f][0] - mn);
            float p1 = __expf(s[f][1] - mn);
            float p2 = __expf(s[f][2] - mn);
            float p3 = __expf(s[f][3] - mn);
            lsum += (p0 + p1) + (p2 + p3);
            f16x4 pk;
            pk.x = (_Float16)p0;
            pk.y = (_Float16)p1;
            pk.z = (_Float16)p2;
            pk.w = (_Float16)p3;
            *(f16x4*)&Pw[c * VP + f * 16 + g * 4] = pk;
        }
        lsum += __shfl_xor(lsum, 16);
        lsum += __shfl_xor(lsum, 32);
        l = l * fsc + lsum;
        // rescale O accumulator; O rows are q = g*4+r -> fetch factors by shfl
        {
            float f0 = __shfl(fsc, g * 4 + 0);
            float f1 = __shfl(fsc, g * 4 + 1);
            float f2 = __shfl(fsc, g * 4 + 2);
            float f3 = __shfl(fsc, g * 4 + 3);
            o[0][0] *= f0; o[0][1] *= f1; o[0][2] *= f2; o[0][3] *= f3;
            o[1][0] *= f0; o[1][1] *= f1; o[1][2] *= f2; o[1][3] *= f3;
        }
        // PV: 4 K-steps of 32 keys, 2 d-fragments
#pragma unroll
        for (int s2 = 0; s2 < 4; ++s2) {
            f16x8 pa = *(const f16x8*)&Pw[c * VP + s2 * 32 + g * 8];
            f16x8 v0 = *(const f16x8*)&Vl[c * VP + s2 * 32 + g * 8];
            f16x8 v1 = *(const f16x8*)&Vl[(16 + c) * VP + s2 * 32 + g * 8];
            o[0] = __builtin_amdgcn_mfma_f32_16x16x32_f16(pa, v0, o[0], 0, 0, 0);
            o[1] = __builtin_amdgcn_mfma_f32_16x16x32_f16(pa, v1, o[1], 0, 0, 0);
        }
        __syncthreads();
    }
    // normalize + write (O rows are q = g*4+r, cols d = n*16 + c)
    const float invl = 1.f / l;
    float i0 = __shfl(invl, g * 4 + 0);
    float i1 = __shfl(invl, g * 4 + 1);
    float i2 = __shfl(invl, g * 4 + 2);
    float i3 = __shfl(invl, g * 4 + 3);
    const int qrow = q0 + w * 16 + g * 4;
#pragma unroll
    for (int n = 0; n < 2; ++n) {
        const int d = h * 32 + n * 16 + c;
        outb[(size_t)(qrow + 0) * D + d] = f2bf(o[n][0] * i0);
        outb[(size_t)(qrow + 1) * D + d] = f2bf(o[n][1] * i1);
        outb[(size_t)(qrow + 2) * D + d] = f2bf(o[n][2] * i2);
        outb[(size_t)(qrow + 3) * D + d] = f2bf(o[n][3] * i3);
    }
}

// ---------------------------------------------------------------------------
// h = LayerNorm(res + proj) * w + b  -> fp32 h AND bf16 hb
// ---------------------------------------------------------------------------
__global__ __launch_bounds__(256) void add_ln(const float* __restrict__ res,
                                              const float* __restrict__ proj,
                                              const float* __restrict__ lw,
                                              const float* __restrict__ lb,
                                              float* __restrict__ hout,
                                              u16* __restrict__ hbout) {
    const int row = blockIdx.x, tid = threadIdx.x;
    __shared__ float red[8];
    const float x0 = res[row * D + tid] + proj[row * D + tid];
    const float x1 = res[row * D + tid + 256] + proj[row * D + tid + 256];
    float s = x0 + x1, s2 = x0 * x0 + x1 * x1;
    for (int o = 32; o > 0; o >>= 1) {
        s += __shfl_down(s, o);
        s2 += __shfl_down(s2, o);
    }
    if ((tid & 63) == 0) {
        red[tid >> 6] = s;
        red[4 + (tid >> 6)] = s2;
    }
    __syncthreads();
    const float mean = (red[0] + red[1] + red[2] + red[3]) * (1.f / 512.f);
    const float var = (red[4] + red[5] + red[6] + red[7]) * (1.f / 512.f) - mean * mean;
    const float r = rsqrtf(var + 1e-5f);
    float y0 = (x0 - mean) * r * lw[tid] + lb[tid];
    float y1 = (x1 - mean) * r * lw[tid + 256] + lb[tid + 256];
    hout[row * D + tid] = y0;
    hout[row * D + tid + 256] = y1;
    hbout[row * D + tid] = f2bf(y0);
    hbout[row * D + tid + 256] = f2bf(y1);
}

// ---------------------------------------------------------------------------
__global__ void logits_kernel(const float* __restrict__ h, const float* __restrict__ pw,
                              const float* __restrict__ pb, const int* __restrict__ rl,
                              const int* __restrict__ tl, const int* __restrict__ pl,
                              float* __restrict__ out) {
    const int n = blockIdx.x * 256 + threadIdx.x;
    if (n >= VOCAB_AUD) return;
    int tot = rl[0] + tl[0] + pl[0];
    int last = tot - 1;
    if (last < 0) last = 0;
    const float* hr = h + last * D;
    float acc = 0.f;
    for (int d = 0; d < D; ++d) acc += hr[d] * pw[d * VOCAB_AUD + n];
    out[n] = acc + pb[n];
}

__global__ void finalize_kernel(const float* __restrict__ logits, const int* __restrict__ rl,
                                const int* __restrict__ tl, const int* __restrict__ pl,
                                float* __restrict__ out) {
    __shared__ float vals[1024];
    __shared__ int idxs[1024];
    const int tid = threadIdx.x;
    float v = logits[tid];
    int bi = tid;
    if (tid == 0 && logits[1024] > v) { v = logits[1024]; bi = 1024; }
    vals[tid] = v;
    idxs[tid] = bi;
    __syncthreads();
    for (int s2 = 512; s2 > 0; s2 >>= 1) {
        if (tid < s2) {
            float ov = vals[tid + s2];
            int oi = idxs[tid + s2];
            if (ov > vals[tid] || (ov == vals[tid] && oi < idxs[tid])) {
                vals[tid] = ov;
                idxs[tid] = oi;
            }
        }
        __syncthreads();
    }
    if (tid == 0) {
        out[1025] = (float)idxs[0];
        out[1026] = (idxs[0] == 1024) ? 1.f : 0.f;
        out[1027] = (float)(rl[0] + tl[0] + pl[0]);
        out[1028] = (float)pl[0];
    }
}

// ---------------------------------------------------------------------------
extern "C" void kernel_launch(void* const* d_in, const int* in_sizes, int n_in,
                              void* d_out, int out_size, void* d_ws, size_t ws_size,
                              hipStream_t stream) {
    const int* prompts = (const int*)d_in[0];
    const int* p_len = (const int*)d_in[1];
    const int* ref_seq = (const int*)d_in[2];
    const int* r_len = (const int*)d_in[3];
    const int* text_seq = (const int*)d_in[4];
    const int* t_len = (const int*)d_in[5];
    const float* ref_bert = (const float*)d_in[6];
    const float* text_bert = (const float*)d_in[7];
    const float* text_emb = (const float*)d_in[8];
    const float* audio_emb = (const float*)d_in[9];
    const float* bert_w = (const float*)d_in[10];
    const float* bert_b = (const float*)d_in[11];
    const float* alpha_text = (const float*)d_in[12];
    const float* alpha_audio = (const float*)d_in[13];
    const float* qkv_w = (const float*)d_in[14];
    const float* qkv_b = (const float*)d_in[15];
    const float* out_w = (const float*)d_in[16];
    const float* out_b = (const float*)d_in[17];
    const float* ln1_w = (const float*)d_in[18];
    const float* ln1_b = (const float*)d_in[19];
    const float* ff1_w = (const float*)d_in[20];
    const float* ff1_b = (const float*)d_in[21];
    const float* ff2_w = (const float*)d_in[22];
    const float* ff2_b = (const float*)d_in[23];
    const float* ln2_w = (const float*)d_in[24];
    const float* ln2_b = (const float*)d_in[25];
    const float* pred_w = (const float*)d_in[26];
    const float* pred_b = (const float*)d_in[27];

    // ---- workspace carve-up ----
    float* ws = (float*)d_ws;
    float* h = ws;                       // 524288 f
    float* proj = h + 524288;            // 524288 f
    float* qkvb = proj + 524288;         // 1572864 f
    float* refp = qkvb + 1572864;        // 131072 f
    float* textp = refp + 131072;        // 131072 f
    u16* hb = (u16*)(textp + 131072);    // 524288 u
    u16* attn_ob = hb + 524288;          // 524288 u
    u16* ffb = attn_ob + 524288;         // 2097152 u (also V^T f16 scratch)
    u16* refT = ffb + 2097152;           // 262144 u
    u16* textT = refT + 262144;          // 262144 u
    u16* bertwT = textT + 262144;        // 524288 u
    u16* qkvh = bertwT + 524288;         // 1572864 u (f16 copy of qkv)
    u16* wbase = qkvh + 1572864;

    const size_t W_QKV = (size_t)D * 3 * D;      // 786432
    const size_t W_OUT = (size_t)D * D;          // 262144
    const size_t W_FF1 = (size_t)D * FF;         // 1048576
    const size_t W_FF2 = (size_t)FF * D;         // 1048576
    const size_t W_ALL = W_QKV + W_OUT + W_FF1 + W_FF2;  // 3145728 per layer

    const size_t need_full = ((char*)(wbase + LAYERS * W_ALL) - (char*)ws);
    const bool full = ws_size >= need_full;

    u16* qkvT = wbase;
    u16* outT = qkvT + (full ? LAYERS * W_QKV : 0);
    u16* ff1T = outT + (full ? LAYERS * W_OUT : 0);
    u16* ff2T = ff1T + (full ? LAYERS * W_FF1 : 0);
    if (!full) {  // per-layer scratch slots
        qkvT = wbase;
        outT = qkvT + W_QKV;
        ff1T = outT + W_OUT;
        ff2T = ff1T + W_FF1;
    }

    float* out = (float*)d_out;
    float* kc = out + 1029;
    float* vc = out + 1029 + (size_t)LAYERS * CACHE_ROWS * D;

    // zero decode-pad rows of caches
    {
        int total4 = LAYERS * (MAX_DECODE * D / 4);
        zero_pads<<<(total4 + 255) / 256, 256, 0, stream>>>(kc, vc);
    }

    // transpose+convert: bert inputs and bert weight
    transpose_cvt<false><<<dim3(256 / 32, 1024 / 32, 1), 256, 0, stream>>>(ref_bert, refT, 1024, 256);
    transpose_cvt<false><<<dim3(256 / 32, 1024 / 32, 1), 256, 0, stream>>>(text_bert, textT, 1024, 256);
    transpose_cvt<false><<<dim3(D / 32, 1024 / 32, 1), 256, 0, stream>>>(bert_w, bertwT, 1024, D);
    if (full) {
        transpose_cvt<false><<<dim3(3 * D / 32, D / 32, LAYERS), 256, 0, stream>>>(qkv_w, qkvT, D, 3 * D);
        transpose_cvt<false><<<dim3(D / 32, D / 32, LAYERS), 256, 0, stream>>>(out_w, outT, D, D);
        transpose_cvt<false><<<dim3(FF / 32, D / 32, LAYERS), 256, 0, stream>>>(ff1_w, ff1T, D, FF);
        transpose_cvt<false><<<dim3(D / 32, FF / 32, LAYERS), 256, 0, stream>>>(ff2_w, ff2T, FF, D);
    }

    // bert projections (MFMA): refp = refT(256x1024) @ bertwT^T + bert_b
    gemm_mfma<false, true, false, false><<<dim3(D / 128, 256 / 128), 256, 0, stream>>>(
        refT, bertwT, bert_b, refp, nullptr, 256, 1024, D);
    gemm_mfma<false, true, false, false><<<dim3(D / 128, 256 / 128), 256, 0, stream>>>(
        textT, bertwT, bert_b, textp, nullptr, 256, 1024, D);

    build_h<<<TOTAL, 256, 0, stream>>>(prompts, p_len, ref_seq, r_len, text_seq, t_len,
                                       text_emb, audio_emb, refp, textp,
                                       alpha_text, alpha_audio, h, hb);

    for (int l = 0; l < LAYERS; ++l) {
        u16 *wQ, *wO, *wF1, *wF2;
        if (full) {
            wQ = qkvT + l * W_QKV;
            wO = outT + l * W_OUT;
            wF1 = ff1T + l * W_FF1;
            wF2 = ff2T + l * W_FF2;
        } else {
            transpose_cvt<false><<<dim3(3 * D / 32, D / 32, 1), 256, 0, stream>>>(
                qkv_w + l * W_QKV, qkvT, D, 3 * D);
            transpose_cvt<false><<<dim3(D / 32, D / 32, 1), 256, 0, stream>>>(
                out_w + l * W_OUT, outT, D, D);
            transpose_cvt<false><<<dim3(FF / 32, D / 32, 1), 256, 0, stream>>>(
                ff1_w + l * W_FF1, ff1T, D, FF);
            transpose_cvt<false><<<dim3(D / 32, FF / 32, 1), 256, 0, stream>>>(
                ff2_w + l * W_FF2, ff2T, FF, D);
            wQ = qkvT; wO = outT; wF1 = ff1T; wF2 = ff2T;
        }
        // qkv = hb @ wQ^T + b  -> f32 (for kv cache) AND f16 (for attention)
        gemm_mfma<false, true, true, true><<<dim3(3 * D / 128, TOTAL / 128), 256, 0, stream>>>(
            hb, wQ, qkv_b + (size_t)l * 3 * D, qkvb, qkvh, TOTAL, D, 3 * D);
        copy_kv<<<TOTAL * (D / 4) / 256, 256, 0, stream>>>(
            qkvb, kc + (size_t)l * CACHE_ROWS * D, vc + (size_t)l * CACHE_ROWS * D);
        // V^T (f16) for attention's B-fragments: vc[1024][512] -> ffb[512][1024]
        transpose_cvt<true><<<dim3(D / 32, 1024 / 32, 1), 256, 0, stream>>>(
            vc + (size_t)l * CACHE_ROWS * D, ffb, 1024, D);
        attn_mfma<<<dim3(H, TOTAL / 64), 256, 0, stream>>>(qkvh, ffb, r_len, t_len, p_len, attn_ob);
        gemm_mfma<false, true, false, false><<<dim3(D / 128, TOTAL / 128), 256, 0, stream>>>(
            attn_ob, wO, out_b + (size_t)l * D, proj, nullptr, TOTAL, D, D);
        add_ln<<<TOTAL, 256, 0, stream>>>(h, proj, ln1_w + l * D, ln1_b + l * D, h, hb);
        gemm_mfma<true, false, true, false><<<dim3(FF / 128, TOTAL / 128), 256, 0, stream>>>(
            hb, wF1, ff1_b + (size_t)l * FF, nullptr, ffb, TOTAL, D, FF);
        gemm_mfma<false, true, false, false><<<dim3(D / 128, TOTAL / 128), 256, 0, stream>>>(
            ffb, wF2, ff2_b + (size_t)l * D, proj, nullptr, TOTAL, FF, D);
        add_ln<<<TOTAL, 256, 0, stream>>>(h, proj, ln2_w + l * D, ln2_b + l * D, h, hb);
    }

    logits_kernel<<<(VOCAB_AUD + 255) / 256, 256, 0, stream>>>(
        h, pred_w, pred_b, r_len, t_len, p_len, out);
    finalize_kernel<<<1, 1024, 0, stream>>>(out, r_len, t_len, p_len, out);
}

// Round 4
// 2620.426 us; speedup vs baseline: 15.9888x; 1.4254x over previous
//
#include <hip/hip_runtime.h>

#define D 512
#define H 16
#define HD 32
#define LAYERS 24
#define FF 2048
#define MAX_DECODE 1500
#define TOTAL 1024
#define CACHE_ROWS (TOTAL + MAX_DECODE)   // 2524
#define VOCAB_AUD 1025

typedef unsigned short u16;
typedef __attribute__((ext_vector_type(8))) __bf16 bf16x8;
typedef __attribute__((ext_vector_type(4))) float f32x4;
typedef __attribute__((ext_vector_type(8))) u16 u16x8;
typedef __attribute__((ext_vector_type(4))) u16 u16x4;
typedef __attribute__((ext_vector_type(8))) _Float16 f16x8;
typedef __attribute__((ext_vector_type(4))) _Float16 f16x4;

__device__ __forceinline__ u16 f2bf(float f) {
    unsigned u = __builtin_bit_cast(unsigned, f);
    u += 0x7fff + ((u >> 16) & 1);   // RNE
    return (u16)(u >> 16);
}

__device__ __forceinline__ u16 f2h(float f) {
    _Float16 h = (_Float16)f;
    return __builtin_bit_cast(u16, h);
}

// ---------------------------------------------------------------------------
// Sinusoidal PE
// ---------------------------------------------------------------------------
__device__ __forceinline__ float pe_val(int pos, int c) {
    int j = c & ~1;
    float div = __expf((float)j * -0.017988946039015984f);  // -log(10000)/512
    float ang = (float)pos * div;
    return (c & 1) ? __cosf(ang) : __sinf(ang);
}

// ---------------------------------------------------------------------------
// Transpose + fp32->bf16 convert:  W[K][N] (layer z) -> WT[N][K]
// grid (N/32, K/32, L), block 256
// ---------------------------------------------------------------------------
__global__ __launch_bounds__(256) void transpose_cvt(const float* __restrict__ W,
                                                     u16* __restrict__ WT,
                                                     int K, int N) {
    const size_t lsz = (size_t)K * N;
    const float* Wl = W + blockIdx.z * lsz;
    u16* WTl = WT + blockIdx.z * lsz;
    __shared__ float T[32][33];
    const int t = threadIdx.x;
    const int k0 = blockIdx.y * 32, n0 = blockIdx.x * 32;
    {
        int r = t >> 5, c = t & 31;
#pragma unroll
        for (int i = 0; i < 4; ++i)
            T[r + 8 * i][c] = Wl[(size_t)(k0 + r + 8 * i) * N + n0 + c];
    }
    __syncthreads();
    {
        int n = t >> 3, cg = t & 7;
        u16x4 o;
#pragma unroll
        for (int j = 0; j < 4; ++j) o[j] = f2bf(T[cg * 4 + j][n]);
        *(u16x4*)&WTl[(size_t)(n0 + n) * K + k0 + cg * 4] = o;
    }
}

// ---------------------------------------------------------------------------
// bf16 MFMA GEMM, tile BMxBM, BK=32, 256 thr (4 waves 2x2).
// C[M,N] = A[M,K] @ BT[N,K]^T + bias.   M,N % BM == 0, K % 32 == 0.
// Reg-staged prefetch: next K-tile's global loads issue before compute.
// QKV epilogue: writes qkvh f16 (Cb), kc/vc f32, vth f16 directly.
// ---------------------------------------------------------------------------
#define AP 40  // LDS pitch (u16): 80B rows, 16B-aligned, conflict-free frags

template <int BM, bool RELU, bool WF32, bool WBF16, bool QKV>
__global__ __launch_bounds__(256) void gemm_mfma(const u16* __restrict__ A,
                                                 const u16* __restrict__ BT,
                                                 const float* __restrict__ bias,
                                                 float* __restrict__ C,
                                                 u16* __restrict__ Cb,
                                                 int M, int K, int N,
                                                 float* __restrict__ kcp,
                                                 float* __restrict__ vcp,
                                                 u16* __restrict__ vthp) {
    constexpr int WT = BM / 2;      // wave tile (square)
    constexpr int MI = WT / 16;     // fragment repeats
    constexpr int SI = BM / 64;     // staging octets per thread
    __shared__ u16 As[BM * AP];
    __shared__ u16 Bs[BM * AP];
    const int tid = threadIdx.x;
    const int lane = tid & 63;
    const int wave = tid >> 6;
    const int wm = wave & 1, wn = wave >> 1;
    const int m0 = blockIdx.y * BM, n0 = blockIdx.x * BM;
    const int cr = lane & 15, qd = lane >> 4;
    f32x4 acc[MI][MI];
#pragma unroll
    for (int i = 0; i < MI; ++i)
#pragma unroll
        for (int j = 0; j < MI; ++j) acc[i][j] = (f32x4){0.f, 0.f, 0.f, 0.f};

    u16x8 ra[SI], rb[SI];
    // prologue: load K-tile 0 into registers
#pragma unroll
    for (int i = 0; i < SI; ++i) {
        int slot = tid + i * 256;
        int r = slot >> 2, c = slot & 3;
        ra[i] = *(const u16x8*)&A[(size_t)(m0 + r) * K + c * 8];
        rb[i] = *(const u16x8*)&BT[(size_t)(n0 + r) * K + c * 8];
    }
    for (int k0 = 0; k0 < K; k0 += 32) {
#pragma unroll
        for (int i = 0; i < SI; ++i) {
            int slot = tid + i * 256;
            int r = slot >> 2, c = slot & 3;
            *(u16x8*)&As[r * AP + c * 8] = ra[i];
            *(u16x8*)&Bs[r * AP + c * 8] = rb[i];
        }
        __syncthreads();
        if (k0 + 32 < K) {  // issue next tile's loads; latency hides under MFMA
#pragma unroll
            for (int i = 0; i < SI; ++i) {
                int slot = tid + i * 256;
                int r = slot >> 2, c = slot & 3;
                ra[i] = *(const u16x8*)&A[(size_t)(m0 + r) * K + k0 + 32 + c * 8];
                rb[i] = *(const u16x8*)&BT[(size_t)(n0 + r) * K + k0 + 32 + c * 8];
            }
        }
        bf16x8 af[MI], bfr[MI];
#pragma unroll
        for (int mi = 0; mi < MI; ++mi)
            af[mi] = *(const bf16x8*)&As[(wm * WT + mi * 16 + cr) * AP + qd * 8];
#pragma unroll
        for (int ni = 0; ni < MI; ++ni)
            bfr[ni] = *(const bf16x8*)&Bs[(wn * WT + ni * 16 + cr) * AP + qd * 8];
#pragma unroll
        for (int mi = 0; mi < MI; ++mi)
#pragma unroll
            for (int ni = 0; ni < MI; ++ni)
                acc[mi][ni] = __builtin_amdgcn_mfma_f32_16x16x32_bf16(
                    af[mi], bfr[ni], acc[mi][ni], 0, 0, 0);
        __syncthreads();
    }
#pragma unroll
    for (int mi = 0; mi < MI; ++mi)
#pragma unroll
        for (int ni = 0; ni < MI; ++ni) {
            const int n = n0 + wn * WT + ni * 16 + cr;
            const int mm0 = m0 + wm * WT + mi * 16 + qd * 4;
            const float bn = bias[n];
            float vv[4];
#pragma unroll
            for (int r = 0; r < 4; ++r) {
                float v = acc[mi][ni][r] + bn;
                if (RELU) v = fmaxf(v, 0.f);
                vv[r] = v;
            }
            if (QKV) {
                // f16 full qkv (attention reads Q,K from here)
#pragma unroll
                for (int r = 0; r < 4; ++r)
                    Cb[(size_t)(mm0 + r) * N + n] = f2h(vv[r]);
                if (n >= 1024) {  // V: cache f32 + V^T f16
#pragma unroll
                    for (int r = 0; r < 4; ++r)
                        vcp[(size_t)(mm0 + r) * D + (n - 1024)] = vv[r];
                    u16x4 pk;
#pragma unroll
                    for (int r = 0; r < 4; ++r) pk[r] = f2h(vv[r]);
                    *(u16x4*)&vthp[(size_t)(n - 1024) * 1024 + mm0] = pk;
                } else if (n >= 512) {  // K: cache f32
#pragma unroll
                    for (int r = 0; r < 4; ++r)
                        kcp[(size_t)(mm0 + r) * D + (n - 512)] = vv[r];
                }
            } else {
#pragma unroll
                for (int r = 0; r < 4; ++r) {
                    if (WF32) C[(size_t)(mm0 + r) * N + n] = vv[r];
                    if (WBF16) Cb[(size_t)(mm0 + r) * N + n] = f2bf(vv[r]);
                }
            }
        }
}

// ---------------------------------------------------------------------------
// Build packed input h (fp32 + bf16)
// ---------------------------------------------------------------------------
__global__ void build_h(const int* __restrict__ prompts, const int* __restrict__ pl,
                        const int* __restrict__ ref_seq, const int* __restrict__ rl,
                        const int* __restrict__ text_seq, const int* __restrict__ tl,
                        const float* __restrict__ text_emb, const float* __restrict__ audio_emb,
                        const float* __restrict__ refproj, const float* __restrict__ textproj,
                        const float* __restrict__ alpha_text, const float* __restrict__ alpha_audio,
                        float* __restrict__ h, u16* __restrict__ hb) {
    const int t = blockIdx.x;
    const int ref_len = rl[0], text_len = tl[0], p_len = pl[0];
    const int x_len = ref_len + text_len;
    const int tot = x_len + p_len;
    const float at = alpha_text[0], aa = alpha_audio[0];
    for (int c = threadIdx.x; c < D; c += 256) {
        float val = 0.f;
        if (t < x_len) {
            float pe = at * pe_val(t, c);
            if (t < ref_len)
                val = text_emb[ref_seq[t] * D + c] + refproj[t * D + c] + pe;
            else
                val = text_emb[text_seq[t - ref_len] * D + c] + textproj[(t - ref_len) * D + c] + pe;
        } else if (t < tot) {
            int i = t - x_len;
            float pe = aa * pe_val(i, c);
            float a = (i < p_len) ? audio_emb[prompts[i] * D + c] : 0.f;
            val = a + pe;
        }
        h[t * D + c] = val;
        hb[t * D + c] = f2bf(val);
    }
}

__global__ void zero_pads(float* __restrict__ kc, float* __restrict__ vc) {
    const int per_layer = MAX_DECODE * D / 4;
    int idx = blockIdx.x * 256 + threadIdx.x;
    int l = idx / per_layer, r = idx % per_layer;
    if (l >= LAYERS) return;
    float4 z = {0.f, 0.f, 0.f, 0.f};
    float* kbase = kc + (size_t)l * CACHE_ROWS * D + (size_t)TOTAL * D;
    float* vbase = vc + (size_t)l * CACHE_ROWS * D + (size_t)TOTAL * D;
    ((float4*)kbase)[r] = z;
    ((float4*)vbase)[r] = z;
}

// ---------------------------------------------------------------------------
// MFMA flash attention.  Block = (head, 64 q rows), 256 thr = 4 waves,
// each wave owns 16 q rows.  Key loop: 8 tiles of 128 keys.
// ---------------------------------------------------------------------------
#define KP 40    // K tile pitch (u16)
#define VP 136   // Vt / P pitch (u16)

__global__ __launch_bounds__(256) void attn_mfma(const u16* __restrict__ qkvh,
                                                 const u16* __restrict__ vth,
                                                 const int* __restrict__ rl,
                                                 const int* __restrict__ tl,
                                                 const int* __restrict__ pl,
                                                 u16* __restrict__ outb) {
    __shared__ u16 lds[128 * KP + 32 * VP + 4 * 16 * VP];
    u16* Kl = lds;                         // [128][KP]
    u16* Vl = lds + 128 * KP;              // [32][VP]
    u16* Pl = lds + 128 * KP + 32 * VP;    // [4 waves][16 q][VP]
    const int h = blockIdx.x;
    const int q0 = blockIdx.y * 64;
    const int t = threadIdx.x;
    const int lane = t & 63, w = t >> 6;
    const int c = lane & 15, g = lane >> 4;
    const int xl = rl[0] + tl[0];
    const int tot = xl + pl[0];
    const float scale = 0.17677669529663687f;  // 1/sqrt(32)
    const int qi = q0 + w * 16 + c;            // this lane's q (stats/P space)
    const int Lq = (qi < tot) ? ((qi < xl) ? xl : qi + 1) : 0;
    f16x8 qf = *(const f16x8*)&qkvh[(size_t)qi * 1536 + h * 32 + g * 8];
    f32x4 o[2];
    o[0] = (f32x4){0.f, 0.f, 0.f, 0.f};
    o[1] = (f32x4){0.f, 0.f, 0.f, 0.f};
    float m = -3.0e38f, l = 0.f;
    u16* Pw = Pl + w * 16 * VP;
    const f32x4 zero = (f32x4){0.f, 0.f, 0.f, 0.f};
    for (int kt = 0; kt < 8; ++kt) {
        {   // stage K tile [128 keys][32 d]
            int row = t >> 1, half = t & 1;
            const u16* src = qkvh + (size_t)(kt * 128 + row) * 1536 + 512 + h * 32 + half * 16;
            *(u16x8*)&Kl[row * KP + half * 16] = *(const u16x8*)(src);
            *(u16x8*)&Kl[row * KP + half * 16 + 8] = *(const u16x8*)(src + 8);
        }
        {   // stage V^T tile [32 d][128 keys] (16 u16 per thread)
            int d = t >> 3, seg = t & 7;
            const u16* src = &vth[(size_t)(h * 32 + d) * 1024 + kt * 128 + seg * 16];
            *(u16x8*)&Vl[d * VP + seg * 16] = *(const u16x8*)(src);
            *(u16x8*)&Vl[d * VP + seg * 16 + 8] = *(const u16x8*)(src + 8);
        }
        __syncthreads();
        // S^T: 8 fragments of 16 keys each
        f32x4 s[8];
#pragma unroll
        for (int f = 0; f < 8; ++f) {
            f16x8 kf = *(const f16x8*)&Kl[(f * 16 + c) * KP + g * 8];
            s[f] = __builtin_amdgcn_mfma_f32_16x16x32_f16(kf, qf, zero, 0, 0, 0);
        }
        float tmax = -3.0e38f;
#pragma unroll
        for (int f = 0; f < 8; ++f)
#pragma unroll
            for (int r = 0; r < 4; ++r) {
                int kg = kt * 128 + f * 16 + g * 4 + r;
                float v = (kg < Lq) ? s[f][r] * scale : -1.0e9f;
                s[f][r] = v;
                tmax = fmaxf(tmax, v);
            }
        tmax = fmaxf(tmax, __shfl_xor(tmax, 16));
        tmax = fmaxf(tmax, __shfl_xor(tmax, 32));
        const float mn = fmaxf(m, tmax);
        const float fsc = __expf(m - mn);
        m = mn;
        float lsum = 0.f;
#pragma unroll
        for (int f = 0; f < 8; ++f) {
            float p0 = __expf(s[f][0] - mn);
            float p1 = __expf(s[f][1] - mn);
            float p2 = __expf(s[f][2] - mn);
            float p3 = __expf(s[f][3] - mn);
            lsum += (p0 + p1) + (p2 + p3);
            f16x4 pk;
            pk.x = (_Float16)p0;
            pk.y = (_Float16)p1;
            pk.z = (_Float16)p2;
            pk.w = (_Float16)p3;
            *(f16x4*)&Pw[c * VP + f * 16 + g * 4] = pk;
        }
        lsum += __shfl_xor(lsum, 16);
        lsum += __shfl_xor(lsum, 32);
        l = l * fsc + lsum;
        {
            float f0 = __shfl(fsc, g * 4 + 0);
            float f1 = __shfl(fsc, g * 4 + 1);
            float f2 = __shfl(fsc, g * 4 + 2);
            float f3 = __shfl(fsc, g * 4 + 3);
            o[0][0] *= f0; o[0][1] *= f1; o[0][2] *= f2; o[0][3] *= f3;
            o[1][0] *= f0; o[1][1] *= f1; o[1][2] *= f2; o[1][3] *= f3;
        }
#pragma unroll
        for (int s2 = 0; s2 < 4; ++s2) {
            f16x8 pa = *(const f16x8*)&Pw[c * VP + s2 * 32 + g * 8];
            f16x8 v0 = *(const f16x8*)&Vl[c * VP + s2 * 32 + g * 8];
            f16x8 v1 = *(const f16x8*)&Vl[(16 + c) * VP + s2 * 32 + g * 8];
            o[0] = __builtin_amdgcn_mfma_f32_16x16x32_f16(pa, v0, o[0], 0, 0, 0);
            o[1] = __builtin_amdgcn_mfma_f32_16x16x32_f16(pa, v1, o[1], 0, 0, 0);
        }
        __syncthreads();
    }
    const float invl = 1.f / l;
    float i0 = __shfl(invl, g * 4 + 0);
    float i1 = __shfl(invl, g * 4 + 1);
    float i2 = __shfl(invl, g * 4 + 2);
    float i3 = __shfl(invl, g * 4 + 3);
    const int qrow = q0 + w * 16 + g * 4;
#pragma unroll
    for (int n = 0; n < 2; ++n) {
        const int d = h * 32 + n * 16 + c;
        outb[(size_t)(qrow + 0) * D + d] = f2bf(o[n][0] * i0);
        outb[(size_t)(qrow + 1) * D + d] = f2bf(o[n][1] * i1);
        outb[(size_t)(qrow + 2) * D + d] = f2bf(o[n][2] * i2);
        outb[(size_t)(qrow + 3) * D + d] = f2bf(o[n][3] * i3);
    }
}

// ---------------------------------------------------------------------------
// h = LayerNorm(res + proj) * w + b  -> fp32 h AND bf16 hb
// ---------------------------------------------------------------------------
__global__ __launch_bounds__(256) void add_ln(const float* __restrict__ res,
                                              const float* __restrict__ proj,
                                              const float* __restrict__ lw,
                                              const float* __restrict__ lb,
                                              float* __restrict__ hout,
                                              u16* __restrict__ hbout) {
    const int row = blockIdx.x, tid = threadIdx.x;
    __shared__ float red[8];
    const float x0 = res[row * D + tid] + proj[row * D + tid];
    const float x1 = res[row * D + tid + 256] + proj[row * D + tid + 256];
    float s = x0 + x1, s2 = x0 * x0 + x1 * x1;
    for (int o = 32; o > 0; o >>= 1) {
        s += __shfl_down(s, o);
        s2 += __shfl_down(s2, o);
    }
    if ((tid & 63) == 0) {
        red[tid >> 6] = s;
        red[4 + (tid >> 6)] = s2;
    }
    __syncthreads();
    const float mean = (red[0] + red[1] + red[2] + red[3]) * (1.f / 512.f);
    const float var = (red[4] + red[5] + red[6] + red[7]) * (1.f / 512.f) - mean * mean;
    const float r = rsqrtf(var + 1e-5f);
    float y0 = (x0 - mean) * r * lw[tid] + lb[tid];
    float y1 = (x1 - mean) * r * lw[tid + 256] + lb[tid + 256];
    hout[row * D + tid] = y0;
    hout[row * D + tid + 256] = y1;
    hbout[row * D + tid] = f2bf(y0);
    hbout[row * D + tid + 256] = f2bf(y1);
}

// ---------------------------------------------------------------------------
__global__ void logits_kernel(const float* __restrict__ h, const float* __restrict__ pw,
                              const float* __restrict__ pb, const int* __restrict__ rl,
                              const int* __restrict__ tl, const int* __restrict__ pl,
                              float* __restrict__ out) {
    const int n = blockIdx.x * 256 + threadIdx.x;
    if (n >= VOCAB_AUD) return;
    int tot = rl[0] + tl[0] + pl[0];
    int last = tot - 1;
    if (last < 0) last = 0;
    const float* hr = h + last * D;
    float acc = 0.f;
    for (int d = 0; d < D; ++d) acc += hr[d] * pw[d * VOCAB_AUD + n];
    out[n] = acc + pb[n];
}

__global__ void finalize_kernel(const float* __restrict__ logits, const int* __restrict__ rl,
                                const int* __restrict__ tl, const int* __restrict__ pl,
                                float* __restrict__ out) {
    __shared__ float vals[1024];
    __shared__ int idxs[1024];
    const int tid = threadIdx.x;
    float v = logits[tid];
    int bi = tid;
    if (tid == 0 && logits[1024] > v) { v = logits[1024]; bi = 1024; }
    vals[tid] = v;
    idxs[tid] = bi;
    __syncthreads();
    for (int s2 = 512; s2 > 0; s2 >>= 1) {
        if (tid < s2) {
            float ov = vals[tid + s2];
            int oi = idxs[tid + s2];
            if (ov > vals[tid] || (ov == vals[tid] && oi < idxs[tid])) {
                vals[tid] = ov;
                idxs[tid] = oi;
            }
        }
        __syncthreads();
    }
    if (tid == 0) {
        out[1025] = (float)idxs[0];
        out[1026] = (idxs[0] == 1024) ? 1.f : 0.f;
        out[1027] = (float)(rl[0] + tl[0] + pl[0]);
        out[1028] = (float)pl[0];
    }
}

// ---------------------------------------------------------------------------
extern "C" void kernel_launch(void* const* d_in, const int* in_sizes, int n_in,
                              void* d_out, int out_size, void* d_ws, size_t ws_size,
                              hipStream_t stream) {
    const int* prompts = (const int*)d_in[0];
    const int* p_len = (const int*)d_in[1];
    const int* ref_seq = (const int*)d_in[2];
    const int* r_len = (const int*)d_in[3];
    const int* text_seq = (const int*)d_in[4];
    const int* t_len = (const int*)d_in[5];
    const float* ref_bert = (const float*)d_in[6];
    const float* text_bert = (const float*)d_in[7];
    const float* text_emb = (const float*)d_in[8];
    const float* audio_emb = (const float*)d_in[9];
    const float* bert_w = (const float*)d_in[10];
    const float* bert_b = (const float*)d_in[11];
    const float* alpha_text = (const float*)d_in[12];
    const float* alpha_audio = (const float*)d_in[13];
    const float* qkv_w = (const float*)d_in[14];
    const float* qkv_b = (const float*)d_in[15];
    const float* out_w = (const float*)d_in[16];
    const float* out_b = (const float*)d_in[17];
    const float* ln1_w = (const float*)d_in[18];
    const float* ln1_b = (const float*)d_in[19];
    const float* ff1_w = (const float*)d_in[20];
    const float* ff1_b = (const float*)d_in[21];
    const float* ff2_w = (const float*)d_in[22];
    const float* ff2_b = (const float*)d_in[23];
    const float* ln2_w = (const float*)d_in[24];
    const float* ln2_b = (const float*)d_in[25];
    const float* pred_w = (const float*)d_in[26];
    const float* pred_b = (const float*)d_in[27];

    // ---- workspace carve-up ----
    float* ws = (float*)d_ws;
    float* h = ws;                       // 524288 f
    float* proj = h + 524288;            // 524288 f
    float* refp = proj + 524288;         // 131072 f
    float* textp = refp + 131072;        // 131072 f
    u16* hb = (u16*)(textp + 131072);    // 524288 u
    u16* attn_ob = hb + 524288;          // 524288 u
    u16* ffb = attn_ob + 524288;         // 2097152 u (V^T f16 scratch, ff1 out)
    u16* refT = ffb + 2097152;           // 262144 u
    u16* textT = refT + 262144;          // 262144 u
    u16* bertwT = textT + 262144;        // 524288 u
    u16* qkvh = bertwT + 524288;         // 1572864 u (f16 copy of qkv)
    u16* wbase = qkvh + 1572864;

    const size_t W_QKV = (size_t)D * 3 * D;      // 786432
    const size_t W_OUT = (size_t)D * D;          // 262144
    const size_t W_FF1 = (size_t)D * FF;         // 1048576
    const size_t W_FF2 = (size_t)FF * D;         // 1048576
    const size_t W_ALL = W_QKV + W_OUT + W_FF1 + W_FF2;  // 3145728 per layer

    const size_t need_full = ((char*)(wbase + LAYERS * W_ALL) - (char*)ws);
    const bool full = ws_size >= need_full;

    u16* qkvT = wbase;
    u16* outT = qkvT + (full ? LAYERS * W_QKV : 0);
    u16* ff1T = outT + (full ? LAYERS * W_OUT : 0);
    u16* ff2T = ff1T + (full ? LAYERS * W_FF1 : 0);
    if (!full) {  // per-layer scratch slots
        qkvT = wbase;
        outT = qkvT + W_QKV;
        ff1T = outT + W_OUT;
        ff2T = ff1T + W_FF1;
    }

    float* out = (float*)d_out;
    float* kc = out + 1029;
    float* vc = out + 1029 + (size_t)LAYERS * CACHE_ROWS * D;

    // zero decode-pad rows of caches
    {
        int total4 = LAYERS * (MAX_DECODE * D / 4);
        zero_pads<<<(total4 + 255) / 256, 256, 0, stream>>>(kc, vc);
    }

    // transpose+convert: bert inputs and bert weight
    transpose_cvt<<<dim3(256 / 32, 1024 / 32, 1), 256, 0, stream>>>(ref_bert, refT, 1024, 256);
    transpose_cvt<<<dim3(256 / 32, 1024 / 32, 1), 256, 0, stream>>>(text_bert, textT, 1024, 256);
    transpose_cvt<<<dim3(D / 32, 1024 / 32, 1), 256, 0, stream>>>(bert_w, bertwT, 1024, D);
    if (full) {
        transpose_cvt<<<dim3(3 * D / 32, D / 32, LAYERS), 256, 0, stream>>>(qkv_w, qkvT, D, 3 * D);
        transpose_cvt<<<dim3(D / 32, D / 32, LAYERS), 256, 0, stream>>>(out_w, outT, D, D);
        transpose_cvt<<<dim3(FF / 32, D / 32, LAYERS), 256, 0, stream>>>(ff1_w, ff1T, D, FF);
        transpose_cvt<<<dim3(D / 32, FF / 32, LAYERS), 256, 0, stream>>>(ff2_w, ff2T, FF, D);
    }

    // bert projections: refp = refT(256x1024) @ bertwT^T + bert_b
    gemm_mfma<64, false, true, false, false><<<dim3(D / 64, 256 / 64), 256, 0, stream>>>(
        refT, bertwT, bert_b, refp, nullptr, 256, 1024, D, nullptr, nullptr, nullptr);
    gemm_mfma<64, false, true, false, false><<<dim3(D / 64, 256 / 64), 256, 0, stream>>>(
        textT, bertwT, bert_b, textp, nullptr, 256, 1024, D, nullptr, nullptr, nullptr);

    build_h<<<TOTAL, 256, 0, stream>>>(prompts, p_len, ref_seq, r_len, text_seq, t_len,
                                       text_emb, audio_emb, refp, textp,
                                       alpha_text, alpha_audio, h, hb);

    for (int l = 0; l < LAYERS; ++l) {
        u16 *wQ, *wO, *wF1, *wF2;
        if (full) {
            wQ = qkvT + l * W_QKV;
            wO = outT + l * W_OUT;
            wF1 = ff1T + l * W_FF1;
            wF2 = ff2T + l * W_FF2;
        } else {
            transpose_cvt<<<dim3(3 * D / 32, D / 32, 1), 256, 0, stream>>>(
                qkv_w + l * W_QKV, qkvT, D, 3 * D);
            transpose_cvt<<<dim3(D / 32, D / 32, 1), 256, 0, stream>>>(
                out_w + l * W_OUT, outT, D, D);
            transpose_cvt<<<dim3(FF / 32, D / 32, 1), 256, 0, stream>>>(
                ff1_w + l * W_FF1, ff1T, D, FF);
            transpose_cvt<<<dim3(D / 32, FF / 32, 1), 256, 0, stream>>>(
                ff2_w + l * W_FF2, ff2T, FF, D);
            wQ = qkvT; wO = outT; wF1 = ff1T; wF2 = ff2T;
        }
        // qkv = hb @ wQ^T + b -> qkvh f16, kc/vc f32, vth(ffb) f16 fused
        gemm_mfma<64, false, false, false, true><<<dim3(3 * D / 64, TOTAL / 64), 256, 0, stream>>>(
            hb, wQ, qkv_b + (size_t)l * 3 * D, nullptr, qkvh, TOTAL, D, 3 * D,
            kc + (size_t)l * CACHE_ROWS * D, vc + (size_t)l * CACHE_ROWS * D, ffb);
        attn_mfma<<<dim3(H, TOTAL / 64), 256, 0, stream>>>(qkvh, ffb, r_len, t_len, p_len, attn_ob);
        gemm_mfma<64, false, true, false, false><<<dim3(D / 64, TOTAL / 64), 256, 0, stream>>>(
            attn_ob, wO, out_b + (size_t)l * D, proj, nullptr, TOTAL, D, D,
            nullptr, nullptr, nullptr);
        add_ln<<<TOTAL, 256, 0, stream>>>(h, proj, ln1_w + l * D, ln1_b + l * D, h, hb);
        gemm_mfma<64, true, false, true, false><<<dim3(FF / 64, TOTAL / 64), 256, 0, stream>>>(
            hb, wF1, ff1_b + (size_t)l * FF, nullptr, ffb, TOTAL, D, FF,
            nullptr, nullptr, nullptr);
        gemm_mfma<64, false, true, false, false><<<dim3(D / 64, TOTAL / 64), 256, 0, stream>>>(
            ffb, wF2, ff2_b + (size_t)l * D, proj, nullptr, TOTAL, FF, D,
            nullptr, nullptr, nullptr);
        add_ln<<<TOTAL, 256, 0, stream>>>(h, proj, ln2_w + l * D, ln2_b + l * D, h, hb);
    }

    logits_kernel<<<(VOCAB_AUD + 255) / 256, 256, 0, stream>>>(
        h, pred_w, pred_b, r_len, t_len, p_len, out);
    finalize_kernel<<<1, 1024, 0, stream>>>(out, r_len, t_len, p_len, out);
}

// Round 5
// 2339.713 us; speedup vs baseline: 17.9071x; 1.1200x over previous
//
#include <hip/hip_runtime.h>

#define D 512
#define H 16
#define HD 32
#define LAYERS 24
#define FF 2048
#define MAX_DECODE 1500
#define TOTAL 1024
#define CACHE_ROWS (TOTAL + MAX_DECODE)   // 2524
#define VOCAB_AUD 1025

typedef unsigned short u16;
typedef __attribute__((ext_vector_type(8))) __bf16 bf16x8;
typedef __attribute__((ext_vector_type(4))) float f32x4;
typedef __attribute__((ext_vector_type(8))) u16 u16x8;
typedef __attribute__((ext_vector_type(4))) u16 u16x4;
typedef __attribute__((ext_vector_type(8))) _Float16 f16x8;
typedef __attribute__((ext_vector_type(4))) _Float16 f16x4;

__device__ __forceinline__ u16 f2bf(float f) {
    unsigned u = __builtin_bit_cast(unsigned, f);
    u += 0x7fff + ((u >> 16) & 1);   // RNE
    return (u16)(u >> 16);
}

__device__ __forceinline__ u16 f2h(float f) {
    _Float16 h = (_Float16)f;
    return __builtin_bit_cast(u16, h);
}

// ---------------------------------------------------------------------------
// Sinusoidal PE
// ---------------------------------------------------------------------------
__device__ __forceinline__ float pe_val(int pos, int c) {
    int j = c & ~1;
    float div = __expf((float)j * -0.017988946039015984f);  // -log(10000)/512
    float ang = (float)pos * div;
    return (c & 1) ? __cosf(ang) : __sinf(ang);
}

// ---------------------------------------------------------------------------
// Transpose + fp32->bf16 convert:  W[K][N] (layer z) -> WT[N][K]
// grid (N/32, K/32, L), block 256
// ---------------------------------------------------------------------------
__global__ __launch_bounds__(256) void transpose_cvt(const float* __restrict__ W,
                                                     u16* __restrict__ WT,
                                                     int K, int N) {
    const size_t lsz = (size_t)K * N;
    const float* Wl = W + blockIdx.z * lsz;
    u16* WTl = WT + blockIdx.z * lsz;
    __shared__ float T[32][33];
    const int t = threadIdx.x;
    const int k0 = blockIdx.y * 32, n0 = blockIdx.x * 32;
    {
        int r = t >> 5, c = t & 31;
#pragma unroll
        for (int i = 0; i < 4; ++i)
            T[r + 8 * i][c] = Wl[(size_t)(k0 + r + 8 * i) * N + n0 + c];
    }
    __syncthreads();
    {
        int n = t >> 3, cg = t & 7;
        u16x4 o;
#pragma unroll
        for (int j = 0; j < 4; ++j) o[j] = f2bf(T[cg * 4 + j][n]);
        *(u16x4*)&WTl[(size_t)(n0 + n) * K + k0 + cg * 4] = o;
    }
}

// ---------------------------------------------------------------------------
// bf16 MFMA GEMM, tile 64x64, BK=64, 256 thr (4 waves 2x2).
// C[M,N] = A[M,K] @ BT[N,K]^T + bias.   M,N % 64 == 0, K % 64 == 0.
// Reg-staged prefetch: next K-tile's global loads issue before compute.
// QKV epilogue: writes qkvh f16 (Cb), kc/vc f32, vth f16 directly.
// ---------------------------------------------------------------------------
#define BP 72  // LDS pitch (u16) for BK=64: 144B rows -> 2-way bank alias only

template <bool RELU, bool WF32, bool WBF16, bool QKV>
__global__ __launch_bounds__(256) void gemm_mfma(const u16* __restrict__ A,
                                                 const u16* __restrict__ BT,
                                                 const float* __restrict__ bias,
                                                 float* __restrict__ C,
                                                 u16* __restrict__ Cb,
                                                 int M, int K, int N,
                                                 float* __restrict__ kcp,
                                                 float* __restrict__ vcp,
                                                 u16* __restrict__ vthp) {
    __shared__ u16 As[64 * BP];
    __shared__ u16 Bs[64 * BP];
    const int tid = threadIdx.x;
    const int lane = tid & 63;
    const int wave = tid >> 6;
    const int wm = wave & 1, wn = wave >> 1;
    const int m0 = blockIdx.y * 64, n0 = blockIdx.x * 64;
    const int cr = lane & 15, qd = lane >> 4;
    f32x4 acc[2][2];
#pragma unroll
    for (int i = 0; i < 2; ++i)
#pragma unroll
        for (int j = 0; j < 2; ++j) acc[i][j] = (f32x4){0.f, 0.f, 0.f, 0.f};

    // staging: 64 rows x 64 cols = 512 octets per matrix, 2 per thread
    u16x8 ra[2], rb[2];
#pragma unroll
    for (int i = 0; i < 2; ++i) {
        int slot = tid + i * 256;
        int r = slot >> 3, c = slot & 7;
        ra[i] = *(const u16x8*)&A[(size_t)(m0 + r) * K + c * 8];
        rb[i] = *(const u16x8*)&BT[(size_t)(n0 + r) * K + c * 8];
    }
    for (int k0 = 0; k0 < K; k0 += 64) {
#pragma unroll
        for (int i = 0; i < 2; ++i) {
            int slot = tid + i * 256;
            int r = slot >> 3, c = slot & 7;
            *(u16x8*)&As[r * BP + c * 8] = ra[i];
            *(u16x8*)&Bs[r * BP + c * 8] = rb[i];
        }
        __syncthreads();
        if (k0 + 64 < K) {  // issue next tile's loads; latency hides under MFMA
#pragma unroll
            for (int i = 0; i < 2; ++i) {
                int slot = tid + i * 256;
                int r = slot >> 3, c = slot & 7;
                ra[i] = *(const u16x8*)&A[(size_t)(m0 + r) * K + k0 + 64 + c * 8];
                rb[i] = *(const u16x8*)&BT[(size_t)(n0 + r) * K + k0 + 64 + c * 8];
            }
        }
        bf16x8 af[2][2], bfr[2][2];
#pragma unroll
        for (int mi = 0; mi < 2; ++mi)
#pragma unroll
            for (int kk = 0; kk < 2; ++kk)
                af[mi][kk] = *(const bf16x8*)&As[(wm * 32 + mi * 16 + cr) * BP + kk * 32 + qd * 8];
#pragma unroll
        for (int ni = 0; ni < 2; ++ni)
#pragma unroll
            for (int kk = 0; kk < 2; ++kk)
                bfr[ni][kk] = *(const bf16x8*)&Bs[(wn * 32 + ni * 16 + cr) * BP + kk * 32 + qd * 8];
#pragma unroll
        for (int kk = 0; kk < 2; ++kk)
#pragma unroll
            for (int mi = 0; mi < 2; ++mi)
#pragma unroll
                for (int ni = 0; ni < 2; ++ni)
                    acc[mi][ni] = __builtin_amdgcn_mfma_f32_16x16x32_bf16(
                        af[mi][kk], bfr[ni][kk], acc[mi][ni], 0, 0, 0);
        __syncthreads();
    }
#pragma unroll
    for (int mi = 0; mi < 2; ++mi)
#pragma unroll
        for (int ni = 0; ni < 2; ++ni) {
            const int n = n0 + wn * 32 + ni * 16 + cr;
            const int mm0 = m0 + wm * 32 + mi * 16 + qd * 4;
            const float bn = bias[n];
            float vv[4];
#pragma unroll
            for (int r = 0; r < 4; ++r) {
                float v = acc[mi][ni][r] + bn;
                if (RELU) v = fmaxf(v, 0.f);
                vv[r] = v;
            }
            if (QKV) {
                // f16 full qkv (attention reads Q,K from here)
#pragma unroll
                for (int r = 0; r < 4; ++r)
                    Cb[(size_t)(mm0 + r) * N + n] = f2h(vv[r]);
                if (n >= 1024) {  // V: cache f32 + V^T f16
#pragma unroll
                    for (int r = 0; r < 4; ++r)
                        vcp[(size_t)(mm0 + r) * D + (n - 1024)] = vv[r];
                    u16x4 pk;
#pragma unroll
                    for (int r = 0; r < 4; ++r) pk[r] = f2h(vv[r]);
                    *(u16x4*)&vthp[(size_t)(n - 1024) * 1024 + mm0] = pk;
                } else if (n >= 512) {  // K: cache f32
#pragma unroll
                    for (int r = 0; r < 4; ++r)
                        kcp[(size_t)(mm0 + r) * D + (n - 512)] = vv[r];
                }
            } else {
#pragma unroll
                for (int r = 0; r < 4; ++r) {
                    if (WF32) C[(size_t)(mm0 + r) * N + n] = vv[r];
                    if (WBF16) Cb[(size_t)(mm0 + r) * N + n] = f2bf(vv[r]);
                }
            }
        }
}

// ---------------------------------------------------------------------------
// Build packed input h (fp32 + bf16)
// ---------------------------------------------------------------------------
__global__ void build_h(const int* __restrict__ prompts, const int* __restrict__ pl,
                        const int* __restrict__ ref_seq, const int* __restrict__ rl,
                        const int* __restrict__ text_seq, const int* __restrict__ tl,
                        const float* __restrict__ text_emb, const float* __restrict__ audio_emb,
                        const float* __restrict__ refproj, const float* __restrict__ textproj,
                        const float* __restrict__ alpha_text, const float* __restrict__ alpha_audio,
                        float* __restrict__ h, u16* __restrict__ hb) {
    const int t = blockIdx.x;
    const int ref_len = rl[0], text_len = tl[0], p_len = pl[0];
    const int x_len = ref_len + text_len;
    const int tot = x_len + p_len;
    const float at = alpha_text[0], aa = alpha_audio[0];
    for (int c = threadIdx.x; c < D; c += 256) {
        float val = 0.f;
        if (t < x_len) {
            float pe = at * pe_val(t, c);
            if (t < ref_len)
                val = text_emb[ref_seq[t] * D + c] + refproj[t * D + c] + pe;
            else
                val = text_emb[text_seq[t - ref_len] * D + c] + textproj[(t - ref_len) * D + c] + pe;
        } else if (t < tot) {
            int i = t - x_len;
            float pe = aa * pe_val(i, c);
            float a = (i < p_len) ? audio_emb[prompts[i] * D + c] : 0.f;
            val = a + pe;
        }
        h[t * D + c] = val;
        hb[t * D + c] = f2bf(val);
    }
}

__global__ void zero_pads(float* __restrict__ kc, float* __restrict__ vc) {
    const int per_layer = MAX_DECODE * D / 4;
    int idx = blockIdx.x * 256 + threadIdx.x;
    int l = idx / per_layer, r = idx % per_layer;
    if (l >= LAYERS) return;
    float4 z = {0.f, 0.f, 0.f, 0.f};
    float* kbase = kc + (size_t)l * CACHE_ROWS * D + (size_t)TOTAL * D;
    float* vbase = vc + (size_t)l * CACHE_ROWS * D + (size_t)TOTAL * D;
    ((float4*)kbase)[r] = z;
    ((float4*)vbase)[r] = z;
}

// ---------------------------------------------------------------------------
// MFMA flash attention.  Block = (head, 64 q rows), 256 thr = 4 waves,
// each wave owns 16 q rows.  Key loop: tiles of 128 keys, causally trimmed
// per block (bit-identical: skipped tiles contribute exactly 0 probability
// and a 1.0 rescale).  Blocks containing pad rows keep all tiles (reference
// gives pad rows uniform attention over all keys).
// ---------------------------------------------------------------------------
#define KP 40    // K tile pitch (u16)
#define VP 136   // Vt / P pitch (u16)

__global__ __launch_bounds__(256) void attn_mfma(const u16* __restrict__ qkvh,
                                                 const u16* __restrict__ vth,
                                                 const int* __restrict__ rl,
                                                 const int* __restrict__ tl,
                                                 const int* __restrict__ pl,
                                                 u16* __restrict__ outb) {
    __shared__ u16 lds[128 * KP + 32 * VP + 4 * 16 * VP];
    u16* Kl = lds;                         // [128][KP]
    u16* Vl = lds + 128 * KP;              // [32][VP]
    u16* Pl = lds + 128 * KP + 32 * VP;    // [4 waves][16 q][VP]
    const int h = blockIdx.x;
    const int q0 = blockIdx.y * 64;
    const int t = threadIdx.x;
    const int lane = t & 63, w = t >> 6;
    const int c = lane & 15, g = lane >> 4;
    const int xl = rl[0] + tl[0];
    const int tot = xl + pl[0];
    const float scale = 0.17677669529663687f;  // 1/sqrt(32)
    const int qi = q0 + w * 16 + c;            // this lane's q (stats/P space)
    const int Lq = (qi < tot) ? ((qi < xl) ? xl : qi + 1) : 0;
    // causal tile trim (block-uniform; only when no pad rows in block)
    int ktmax = 8;
    if (q0 + 64 <= tot) {
        int Lmax = xl > (q0 + 64) ? xl : (q0 + 64);
        ktmax = (Lmax + 127) >> 7;
    }
    f16x8 qf = *(const f16x8*)&qkvh[(size_t)qi * 1536 + h * 32 + g * 8];
    f32x4 o[2];
    o[0] = (f32x4){0.f, 0.f, 0.f, 0.f};
    o[1] = (f32x4){0.f, 0.f, 0.f, 0.f};
    float m = -3.0e38f, l = 0.f;
    u16* Pw = Pl + w * 16 * VP;
    const f32x4 zero = (f32x4){0.f, 0.f, 0.f, 0.f};
    for (int kt = 0; kt < ktmax; ++kt) {
        {   // stage K tile [128 keys][32 d]
            int row = t >> 1, half = t & 1;
            const u16* src = qkvh + (size_t)(kt * 128 + row) * 1536 + 512 + h * 32 + half * 16;
            *(u16x8*)&Kl[row * KP + half * 16] = *(const u16x8*)(src);
            *(u16x8*)&Kl[row * KP + half * 16 + 8] = *(const u16x8*)(src + 8);
        }
        {   // stage V^T tile [32 d][128 keys] (16 u16 per thread)
            int d = t >> 3, seg = t & 7;
            const u16* src = &vth[(size_t)(h * 32 + d) * 1024 + kt * 128 + seg * 16];
            *(u16x8*)&Vl[d * VP + seg * 16] = *(const u16x8*)(src);
            *(u16x8*)&Vl[d * VP + seg * 16 + 8] = *(const u16x8*)(src + 8);
        }
        __syncthreads();
        // S^T: 8 fragments of 16 keys each
        f32x4 s[8];
#pragma unroll
        for (int f = 0; f < 8; ++f) {
            f16x8 kf = *(const f16x8*)&Kl[(f * 16 + c) * KP + g * 8];
            s[f] = __builtin_amdgcn_mfma_f32_16x16x32_f16(kf, qf, zero, 0, 0, 0);
        }
        float tmax = -3.0e38f;
#pragma unroll
        for (int f = 0; f < 8; ++f)
#pragma unroll
            for (int r = 0; r < 4; ++r) {
                int kg = kt * 128 + f * 16 + g * 4 + r;
                float v = (kg < Lq) ? s[f][r] * scale : -1.0e9f;
                s[f][r] = v;
                tmax = fmaxf(tmax, v);
            }
        tmax = fmaxf(tmax, __shfl_xor(tmax, 16));
        tmax = fmaxf(tmax, __shfl_xor(tmax, 32));
        const float mn = fmaxf(m, tmax);
        const float fsc = __expf(m - mn);
        m = mn;
        float lsum = 0.f;
#pragma unroll
        for (int f = 0; f < 8; ++f) {
            float p0 = __expf(s[f][0] - mn);
            float p1 = __expf(s[f][1] - mn);
            float p2 = __expf(s[f][2] - mn);
            float p3 = __expf(s[f][3] - mn);
            lsum += (p0 + p1) + (p2 + p3);
            f16x4 pk;
            pk.x = (_Float16)p0;
            pk.y = (_Float16)p1;
            pk.z = (_Float16)p2;
            pk.w = (_Float16)p3;
            *(f16x4*)&Pw[c * VP + f * 16 + g * 4] = pk;
        }
        lsum += __shfl_xor(lsum, 16);
        lsum += __shfl_xor(lsum, 32);
        l = l * fsc + lsum;
        {
            float f0 = __shfl(fsc, g * 4 + 0);
            float f1 = __shfl(fsc, g * 4 + 1);
            float f2 = __shfl(fsc, g * 4 + 2);
            float f3 = __shfl(fsc, g * 4 + 3);
            o[0][0] *= f0; o[0][1] *= f1; o[0][2] *= f2; o[0][3] *= f3;
            o[1][0] *= f0; o[1][1] *= f1; o[1][2] *= f2; o[1][3] *= f3;
        }
#pragma unroll
        for (int s2 = 0; s2 < 4; ++s2) {
            f16x8 pa = *(const f16x8*)&Pw[c * VP + s2 * 32 + g * 8];
            f16x8 v0 = *(const f16x8*)&Vl[c * VP + s2 * 32 + g * 8];
            f16x8 v1 = *(const f16x8*)&Vl[(16 + c) * VP + s2 * 32 + g * 8];
            o[0] = __builtin_amdgcn_mfma_f32_16x16x32_f16(pa, v0, o[0], 0, 0, 0);
            o[1] = __builtin_amdgcn_mfma_f32_16x16x32_f16(pa, v1, o[1], 0, 0, 0);
        }
        __syncthreads();
    }
    const float invl = 1.f / l;
    float i0 = __shfl(invl, g * 4 + 0);
    float i1 = __shfl(invl, g * 4 + 1);
    float i2 = __shfl(invl, g * 4 + 2);
    float i3 = __shfl(invl, g * 4 + 3);
    const int qrow = q0 + w * 16 + g * 4;
#pragma unroll
    for (int n = 0; n < 2; ++n) {
        const int d = h * 32 + n * 16 + c;
        outb[(size_t)(qrow + 0) * D + d] = f2bf(o[n][0] * i0);
        outb[(size_t)(qrow + 1) * D + d] = f2bf(o[n][1] * i1);
        outb[(size_t)(qrow + 2) * D + d] = f2bf(o[n][2] * i2);
        outb[(size_t)(qrow + 3) * D + d] = f2bf(o[n][3] * i3);
    }
}

// ---------------------------------------------------------------------------
// h = LayerNorm(res + proj) * w + b  -> fp32 h AND bf16 hb
// ---------------------------------------------------------------------------
__global__ __launch_bounds__(256) void add_ln(const float* __restrict__ res,
                                              const float* __restrict__ proj,
                                              const float* __restrict__ lw,
                                              const float* __restrict__ lb,
                                              float* __restrict__ hout,
                                              u16* __restrict__ hbout) {
    const int row = blockIdx.x, tid = threadIdx.x;
    __shared__ float red[8];
    const float x0 = res[row * D + tid] + proj[row * D + tid];
    const float x1 = res[row * D + tid + 256] + proj[row * D + tid + 256];
    float s = x0 + x1, s2 = x0 * x0 + x1 * x1;
    for (int o = 32; o > 0; o >>= 1) {
        s += __shfl_down(s, o);
        s2 += __shfl_down(s2, o);
    }
    if ((tid & 63) == 0) {
        red[tid >> 6] = s;
        red[4 + (tid >> 6)] = s2;
    }
    __syncthreads();
    const float mean = (red[0] + red[1] + red[2] + red[3]) * (1.f / 512.f);
    const float var = (red[4] + red[5] + red[6] + red[7]) * (1.f / 512.f) - mean * mean;
    const float r = rsqrtf(var + 1e-5f);
    float y0 = (x0 - mean) * r * lw[tid] + lb[tid];
    float y1 = (x1 - mean) * r * lw[tid + 256] + lb[tid + 256];
    hout[row * D + tid] = y0;
    hout[row * D + tid + 256] = y1;
    hbout[row * D + tid] = f2bf(y0);
    hbout[row * D + tid + 256] = f2bf(y1);
}

// ---------------------------------------------------------------------------
__global__ void logits_kernel(const float* __restrict__ h, const float* __restrict__ pw,
                              const float* __restrict__ pb, const int* __restrict__ rl,
                              const int* __restrict__ tl, const int* __restrict__ pl,
                              float* __restrict__ out) {
    const int n = blockIdx.x * 256 + threadIdx.x;
    if (n >= VOCAB_AUD) return;
    int tot = rl[0] + tl[0] + pl[0];
    int last = tot - 1;
    if (last < 0) last = 0;
    const float* hr = h + last * D;
    float acc = 0.f;
    for (int d = 0; d < D; ++d) acc += hr[d] * pw[d * VOCAB_AUD + n];
    out[n] = acc + pb[n];
}

__global__ void finalize_kernel(const float* __restrict__ logits, const int* __restrict__ rl,
                                const int* __restrict__ tl, const int* __restrict__ pl,
                                float* __restrict__ out) {
    __shared__ float vals[1024];
    __shared__ int idxs[1024];
    const int tid = threadIdx.x;
    float v = logits[tid];
    int bi = tid;
    if (tid == 0 && logits[1024] > v) { v = logits[1024]; bi = 1024; }
    vals[tid] = v;
    idxs[tid] = bi;
    __syncthreads();
    for (int s2 = 512; s2 > 0; s2 >>= 1) {
        if (tid < s2) {
            float ov = vals[tid + s2];
            int oi = idxs[tid + s2];
            if (ov > vals[tid] || (ov == vals[tid] && oi < idxs[tid])) {
                vals[tid] = ov;
                idxs[tid] = oi;
            }
        }
        __syncthreads();
    }
    if (tid == 0) {
        out[1025] = (float)idxs[0];
        out[1026] = (idxs[0] == 1024) ? 1.f : 0.f;
        out[1027] = (float)(rl[0] + tl[0] + pl[0]);
        out[1028] = (float)pl[0];
    }
}

// ---------------------------------------------------------------------------
extern "C" void kernel_launch(void* const* d_in, const int* in_sizes, int n_in,
                              void* d_out, int out_size, void* d_ws, size_t ws_size,
                              hipStream_t stream) {
    const int* prompts = (const int*)d_in[0];
    const int* p_len = (const int*)d_in[1];
    const int* ref_seq = (const int*)d_in[2];
    const int* r_len = (const int*)d_in[3];
    const int* text_seq = (const int*)d_in[4];
    const int* t_len = (const int*)d_in[5];
    const float* ref_bert = (const float*)d_in[6];
    const float* text_bert = (const float*)d_in[7];
    const float* text_emb = (const float*)d_in[8];
    const float* audio_emb = (const float*)d_in[9];
    const float* bert_w = (const float*)d_in[10];
    const float* bert_b = (const float*)d_in[11];
    const float* alpha_text = (const float*)d_in[12];
    const float* alpha_audio = (const float*)d_in[13];
    const float* qkv_w = (const float*)d_in[14];
    const float* qkv_b = (const float*)d_in[15];
    const float* out_w = (const float*)d_in[16];
    const float* out_b = (const float*)d_in[17];
    const float* ln1_w = (const float*)d_in[18];
    const float* ln1_b = (const float*)d_in[19];
    const float* ff1_w = (const float*)d_in[20];
    const float* ff1_b = (const float*)d_in[21];
    const float* ff2_w = (const float*)d_in[22];
    const float* ff2_b = (const float*)d_in[23];
    const float* ln2_w = (const float*)d_in[24];
    const float* ln2_b = (const float*)d_in[25];
    const float* pred_w = (const float*)d_in[26];
    const float* pred_b = (const float*)d_in[27];

    // ---- workspace carve-up ----
    float* ws = (float*)d_ws;
    float* h = ws;                       // 524288 f
    float* proj = h + 524288;            // 524288 f
    float* refp = proj + 524288;         // 131072 f
    float* textp = refp + 131072;        // 131072 f
    u16* hb = (u16*)(textp + 131072);    // 524288 u
    u16* attn_ob = hb + 524288;          // 524288 u
    u16* ffb = attn_ob + 524288;         // 2097152 u (V^T f16 scratch, ff1 out)
    u16* refT = ffb + 2097152;           // 262144 u
    u16* textT = refT + 262144;          // 262144 u
    u16* bertwT = textT + 262144;        // 524288 u
    u16* qkvh = bertwT + 524288;         // 1572864 u (f16 copy of qkv)
    u16* wbase = qkvh + 1572864;

    const size_t W_QKV = (size_t)D * 3 * D;      // 786432
    const size_t W_OUT = (size_t)D * D;          // 262144
    const size_t W_FF1 = (size_t)D * FF;         // 1048576
    const size_t W_FF2 = (size_t)FF * D;         // 1048576
    const size_t W_ALL = W_QKV + W_OUT + W_FF1 + W_FF2;  // 3145728 per layer

    const size_t need_full = ((char*)(wbase + LAYERS * W_ALL) - (char*)ws);
    const bool full = ws_size >= need_full;

    u16* qkvT = wbase;
    u16* outT = qkvT + (full ? LAYERS * W_QKV : 0);
    u16* ff1T = outT + (full ? LAYERS * W_OUT : 0);
    u16* ff2T = ff1T + (full ? LAYERS * W_FF1 : 0);
    if (!full) {  // per-layer scratch slots
        qkvT = wbase;
        outT = qkvT + W_QKV;
        ff1T = outT + W_OUT;
        ff2T = ff1T + W_FF1;
    }

    float* out = (float*)d_out;
    float* kc = out + 1029;
    float* vc = out + 1029 + (size_t)LAYERS * CACHE_ROWS * D;

    // zero decode-pad rows of caches
    {
        int total4 = LAYERS * (MAX_DECODE * D / 4);
        zero_pads<<<(total4 + 255) / 256, 256, 0, stream>>>(kc, vc);
    }

    // transpose+convert: bert inputs and bert weight
    transpose_cvt<<<dim3(256 / 32, 1024 / 32, 1), 256, 0, stream>>>(ref_bert, refT, 1024, 256);
    transpose_cvt<<<dim3(256 / 32, 1024 / 32, 1), 256, 0, stream>>>(text_bert, textT, 1024, 256);
    transpose_cvt<<<dim3(D / 32, 1024 / 32, 1), 256, 0, stream>>>(bert_w, bertwT, 1024, D);
    if (full) {
        transpose_cvt<<<dim3(3 * D / 32, D / 32, LAYERS), 256, 0, stream>>>(qkv_w, qkvT, D, 3 * D);
        transpose_cvt<<<dim3(D / 32, D / 32, LAYERS), 256, 0, stream>>>(out_w, outT, D, D);
        transpose_cvt<<<dim3(FF / 32, D / 32, LAYERS), 256, 0, stream>>>(ff1_w, ff1T, D, FF);
        transpose_cvt<<<dim3(D / 32, FF / 32, LAYERS), 256, 0, stream>>>(ff2_w, ff2T, FF, D);
    }

    // bert projections: refp = refT(256x1024) @ bertwT^T + bert_b
    gemm_mfma<false, true, false, false><<<dim3(D / 64, 256 / 64), 256, 0, stream>>>(
        refT, bertwT, bert_b, refp, nullptr, 256, 1024, D, nullptr, nullptr, nullptr);
    gemm_mfma<false, true, false, false><<<dim3(D / 64, 256 / 64), 256, 0, stream>>>(
        textT, bertwT, bert_b, textp, nullptr, 256, 1024, D, nullptr, nullptr, nullptr);

    build_h<<<TOTAL, 256, 0, stream>>>(prompts, p_len, ref_seq, r_len, text_seq, t_len,
                                       text_emb, audio_emb, refp, textp,
                                       alpha_text, alpha_audio, h, hb);

    for (int l = 0; l < LAYERS; ++l) {
        u16 *wQ, *wO, *wF1, *wF2;
        if (full) {
            wQ = qkvT + l * W_QKV;
            wO = outT + l * W_OUT;
            wF1 = ff1T + l * W_FF1;
            wF2 = ff2T + l * W_FF2;
        } else {
            transpose_cvt<<<dim3(3 * D / 32, D / 32, 1), 256, 0, stream>>>(
                qkv_w + l * W_QKV, qkvT, D, 3 * D);
            transpose_cvt<<<dim3(D / 32, D / 32, 1), 256, 0, stream>>>(
                out_w + l * W_OUT, outT, D, D);
            transpose_cvt<<<dim3(FF / 32, D / 32, 1), 256, 0, stream>>>(
                ff1_w + l * W_FF1, ff1T, D, FF);
            transpose_cvt<<<dim3(D / 32, FF / 32, 1), 256, 0, stream>>>(
                ff2_w + l * W_FF2, ff2T, FF, D);
            wQ = qkvT; wO = outT; wF1 = ff1T; wF2 = ff2T;
        }
        // qkv = hb @ wQ^T + b -> qkvh f16, kc/vc f32, vth(ffb) f16 fused
        gemm_mfma<false, false, false, true><<<dim3(3 * D / 64, TOTAL / 64), 256, 0, stream>>>(
            hb, wQ, qkv_b + (size_t)l * 3 * D, nullptr, qkvh, TOTAL, D, 3 * D,
            kc + (size_t)l * CACHE_ROWS * D, vc + (size_t)l * CACHE_ROWS * D, ffb);
        attn_mfma<<<dim3(H, TOTAL / 64), 256, 0, stream>>>(qkvh, ffb, r_len, t_len, p_len, attn_ob);
        gemm_mfma<false, true, false, false><<<dim3(D / 64, TOTAL / 64), 256, 0, stream>>>(
            attn_ob, wO, out_b + (size_t)l * D, proj, nullptr, TOTAL, D, D,
            nullptr, nullptr, nullptr);
        add_ln<<<TOTAL, 256, 0, stream>>>(h, proj, ln1_w + l * D, ln1_b + l * D, h, hb);
        gemm_mfma<true, false, true, false><<<dim3(FF / 64, TOTAL / 64), 256, 0, stream>>>(
            hb, wF1, ff1_b + (size_t)l * FF, nullptr, ffb, TOTAL, D, FF,
            nullptr, nullptr, nullptr);
        gemm_mfma<false, true, false, false><<<dim3(D / 64, TOTAL / 64), 256, 0, stream>>>(
            ffb, wF2, ff2_b + (size_t)l * D, proj, nullptr, TOTAL, FF, D,
            nullptr, nullptr, nullptr);
        add_ln<<<TOTAL, 256, 0, stream>>>(h, proj, ln2_w + l * D, ln2_b + l * D, h, hb);
    }

    logits_kernel<<<(VOCAB_AUD + 255) / 256, 256, 0, stream>>>(
        h, pred_w, pred_b, r_len, t_len, p_len, out);
    finalize_kernel<<<1, 1024, 0, stream>>>(out, r_len, t_len, p_len, out);
}